// Round 1
// baseline (550.097 us; speedup 1.0000x reference)
//
#include <hip/hip_runtime.h>
#include <cstddef>
#include <cstdint>

typedef __bf16 bf16;
typedef __bf16 bf16x4 __attribute__((ext_vector_type(4)));
typedef __bf16 bf16x8 __attribute__((ext_vector_type(8)));
typedef float f32x4 __attribute__((ext_vector_type(4)));

#define AS1C(p) ((const __attribute__((address_space(1))) void*)(p))
#define AS3(p)  ((__attribute__((address_space(3))) void*)(p))

#define MROWS 16384
#define HDIM 2560
#define EDIM 1024
#define LSEQ 4096

static __device__ const int kHeadOff[8] = {0, 250007, 500020, 750047,
                                           1000078, 1250115, 1500158, 1750207};

// ---------------- K1: gather emb rows -> bf16 E [MROWS][1024] ----------------
__global__ __launch_bounds__(256) void k_gather(const int* __restrict__ hidx,
                                                const float* __restrict__ emb,
                                                bf16* __restrict__ E) {
  const int m = blockIdx.x;
  const int t = threadIdx.x;
  const int head = t >> 5;          // 8 heads x 32 threads
  const int e4 = (t & 31) * 4;      // 4 floats per thread
  const int rid = hidx[m * 8 + head] + kHeadOff[head];
  const float4 v = *(const float4*)(emb + (size_t)rid * 128 + e4);
  bf16x4 o;
  o[0] = (bf16)v.x; o[1] = (bf16)v.y; o[2] = (bf16)v.z; o[3] = (bf16)v.w;
  *(bf16x4*)(E + (size_t)m * EDIM + head * 128 + e4) = o;
}

// ---------------- fp32 -> bf16 bulk convert (weights) ----------------
__global__ __launch_bounds__(256) void k_cvt(const float* __restrict__ src,
                                             bf16* __restrict__ dst, int n) {
  int i = (blockIdx.x * 256 + threadIdx.x) * 8;
  if (i + 8 > n) return;
  float4 a = *(const float4*)(src + i);
  float4 b = *(const float4*)(src + i + 4);
  bf16x8 o;
  o[0] = (bf16)a.x; o[1] = (bf16)a.y; o[2] = (bf16)a.z; o[3] = (bf16)a.w;
  o[4] = (bf16)b.x; o[5] = (bf16)b.y; o[6] = (bf16)b.z; o[7] = (bf16)b.w;
  *(bf16x8*)(dst + i) = o;
}

// ---------------- K2: GEMM C[m][n] = sum_k A[m][k] * W[n][k] ----------------
// m97 structure: 128x128 tile, BK=32, 4 waves (2x2), 4x4 16x16x32 frags/wave,
// global_load_lds width-16 staging, linear LDS [128][32].
#define BM 128
#define BN 128
#define BK 32

__global__ __launch_bounds__(256) void k_gemm(const bf16* __restrict__ A,
                                              const bf16* __restrict__ Wv,
                                              const bf16* __restrict__ Wk,
                                              bf16* __restrict__ Vt,
                                              bf16* __restrict__ Kt) {
  __shared__ __attribute__((aligned(16))) bf16 lA[BM * BK];  // 8 KB
  __shared__ __attribute__((aligned(16))) bf16 lB[BN * BK];  // 8 KB

  const int tid = threadIdx.x;
  const int wave = tid >> 6, lane = tid & 63;
  const int wm = wave >> 1, wn = wave & 1;
  const int m0 = blockIdx.y * BM;
  int n0 = blockIdx.x * BN;            // 0..5119 over concat(v,k)
  const bf16* W;
  bf16* Out;
  if (n0 < HDIM) { W = Wv; Out = Vt; } else { W = Wk; Out = Kt; n0 -= HDIM; }

  f32x4 acc[4][4] = {};

  const int r16 = lane & 15;
  const int khalf = lane >> 4;         // 0..3
  const int kOffE = khalf * 8;         // k element offset of this lane's frag

  // staging geometry: chunk lin = iss*256 + tid covers 16B; row=lin>>2, c8=(lin&3)*8
  const int srow = tid >> 2;
  const int sc8 = (tid & 3) * 8;

  for (int k0 = 0; k0 < EDIM; k0 += BK) {
    __syncthreads();  // previous iter's LDS reads done before overwrite
#pragma unroll
    for (int iss = 0; iss < 2; ++iss) {
      const int row = iss * 64 + srow;
      const bf16* ga = A + (size_t)(m0 + row) * EDIM + k0 + sc8;
      __builtin_amdgcn_global_load_lds(AS1C(ga),
          AS3((char*)lA + iss * 4096 + wave * 1024), 16, 0, 0);
      const bf16* gb = W + (size_t)(n0 + row) * EDIM + k0 + sc8;
      __builtin_amdgcn_global_load_lds(AS1C(gb),
          AS3((char*)lB + iss * 4096 + wave * 1024), 16, 0, 0);
    }
    __syncthreads();  // compiler drains vmcnt before barrier -> data visible

    bf16x8 aF[4], bF[4];
#pragma unroll
    for (int mi = 0; mi < 4; ++mi)
      aF[mi] = *(const bf16x8*)&lA[(wm * 64 + mi * 16 + r16) * BK + kOffE];
#pragma unroll
    for (int nj = 0; nj < 4; ++nj)
      bF[nj] = *(const bf16x8*)&lB[(wn * 64 + nj * 16 + r16) * BK + kOffE];
#pragma unroll
    for (int mi = 0; mi < 4; ++mi)
#pragma unroll
      for (int nj = 0; nj < 4; ++nj)
        acc[mi][nj] = __builtin_amdgcn_mfma_f32_16x16x32_bf16(
            aF[mi], bF[nj], acc[mi][nj], 0, 0, 0);
  }

  // epilogue: C/D frag mapping col=lane&15, row=(lane>>4)*4+r
#pragma unroll
  for (int mi = 0; mi < 4; ++mi) {
#pragma unroll
    for (int nj = 0; nj < 4; ++nj) {
      const int col = n0 + wn * 64 + nj * 16 + r16;
#pragma unroll
      for (int r = 0; r < 4; ++r) {
        const int row = m0 + wm * 64 + mi * 16 + khalf * 4 + r;
        Out[(size_t)row * HDIM + col] = (bf16)acc[mi][nj][r];
      }
    }
  }
}

// ---------------- block reduction over 5 waves (320 threads) ----------------
__device__ __forceinline__ float block_sum(float v, float* sbuf) {
#pragma unroll
  for (int o = 32; o > 0; o >>= 1) v += __shfl_xor(v, o);
  __syncthreads();  // protect sbuf from previous use
  if ((threadIdx.x & 63) == 0) sbuf[threadIdx.x >> 6] = v;
  __syncthreads();
  return sbuf[0] + sbuf[1] + sbuf[2] + sbuf[3] + sbuf[4];
}

// ---------------- K3: per-row gating ----------------
// reads hidden fp32, k_t bf16, v_t bf16; writes v_tilde (over k_t buffer), v_n
__global__ __launch_bounds__(320) void k_gate(const float* __restrict__ hidden,
                                              bf16* kt_vtil,  // aliased in/out
                                              const bf16* __restrict__ Vt,
                                              const float* __restrict__ g_h,
                                              const float* __restrict__ g_k,
                                              const float* __restrict__ g_v,
                                              bf16* __restrict__ Vn) {
  __shared__ float sbuf[5];
  const int m = blockIdx.x;
  const int t = threadIdx.x;
  const int h0 = t * 8;
  const size_t base = (size_t)m * HDIM + h0;

  float hx[8];
  *(float4*)&hx[0] = *(const float4*)(hidden + base);
  *(float4*)&hx[4] = *(const float4*)(hidden + base + 4);
  float ss = 0.f;
#pragma unroll
  for (int i = 0; i < 8; ++i) ss += hx[i] * hx[i];
  const float inv_h = rsqrtf(block_sum(ss, sbuf) * (1.f / HDIM) + 1e-6f);

  const bf16x8 kv = *(const bf16x8*)(kt_vtil + base);
  float kx[8];
  ss = 0.f;
#pragma unroll
  for (int i = 0; i < 8; ++i) { kx[i] = (float)kv[i]; ss += kx[i] * kx[i]; }
  const float inv_k = rsqrtf(block_sum(ss, sbuf) * (1.f / HDIM) + 1e-6f);

  float gh[8], gk[8];
  *(float4*)&gh[0] = *(const float4*)(g_h + h0);
  *(float4*)&gh[4] = *(const float4*)(g_h + h0 + 4);
  *(float4*)&gk[0] = *(const float4*)(g_k + h0);
  *(float4*)&gk[4] = *(const float4*)(g_k + h0 + 4);
  float d = 0.f;
#pragma unroll
  for (int i = 0; i < 8; ++i)
    d += (hx[i] * inv_h * gh[i]) * (kx[i] * inv_k * gk[i]);
  const float dot = block_sum(d, sbuf) * 0.019764235f;  // 1/sqrt(2560)
  float stable = sqrtf(fmaxf(fabsf(dot), 1e-6f));
  stable = (dot < 0.f) ? -stable : stable;
  if (dot == 0.f) stable = 0.f;
  const float alpha = 1.f / (1.f + expf(-stable));

  const bf16x8 vv = *(const bf16x8*)(Vt + base);
  float vt[8];
  ss = 0.f;
#pragma unroll
  for (int i = 0; i < 8; ++i) {
    vt[i] = alpha * (float)vv[i];
    ss += vt[i] * vt[i];
  }
  bf16x8 vtl;
#pragma unroll
  for (int i = 0; i < 8; ++i) vtl[i] = (bf16)vt[i];
  *(bf16x8*)(kt_vtil + base) = vtl;  // v_tilde replaces k_t (same offsets)

  const float inv_v = rsqrtf(block_sum(ss, sbuf) * (1.f / HDIM) + 1e-6f);
  float gv[8];
  *(float4*)&gv[0] = *(const float4*)(g_v + h0);
  *(float4*)&gv[4] = *(const float4*)(g_v + h0 + 4);
  bf16x8 vn;
#pragma unroll
  for (int i = 0; i < 8; ++i) vn[i] = (bf16)(vt[i] * inv_v * gv[i]);
  *(bf16x8*)(Vn + base) = vn;
}

// ---------------- K4: causal depthwise conv + SiLU + residuals ----------------
__global__ __launch_bounds__(320) void k_conv(const float* __restrict__ hidden,
                                              const bf16* __restrict__ Vn,
                                              const bf16* __restrict__ Vtil,
                                              const float* __restrict__ conv_w,
                                              const float* __restrict__ conv_b,
                                              float* __restrict__ out) {
  const int m = blockIdx.x;
  const int l = m & (LSEQ - 1);
  const int bb = m >> 12;
  const int t = threadIdx.x;
  const int h0 = t * 8;
  const size_t base = (size_t)m * HDIM + h0;

  float4 cw[8];
#pragma unroll
  for (int i = 0; i < 8; ++i)
    cw[i] = *(const float4*)(conv_w + (size_t)(h0 + i) * 4);

  float acc[8];
  *(float4*)&acc[0] = *(const float4*)(conv_b + h0);
  *(float4*)&acc[4] = *(const float4*)(conv_b + h0 + 4);

#pragma unroll
  for (int j = 0; j < 4; ++j) {
    const int lj = l - 3 + j;
    if (lj < 0) continue;
    const bf16x8 x =
        *(const bf16x8*)(Vn + ((size_t)(bb * LSEQ + lj) * HDIM + h0));
#pragma unroll
    for (int i = 0; i < 8; ++i) {
      const float w = ((const float*)&cw[i])[j];
      acc[i] += w * (float)x[i];
    }
  }

  const bf16x8 vt = *(const bf16x8*)(Vtil + base);
  float hx[8];
  *(float4*)&hx[0] = *(const float4*)(hidden + base);
  *(float4*)&hx[4] = *(const float4*)(hidden + base + 4);
  float o[8];
#pragma unroll
  for (int i = 0; i < 8; ++i) {
    const float c = acc[i];
    const float y = c / (1.f + expf(-c));  // silu
    o[i] = hx[i] + y + (float)vt[i];
  }
  *(float4*)(out + base) = *(float4*)&o[0];
  *(float4*)(out + base + 4) = *(float4*)&o[4];
}

// ---------------- launcher ----------------
extern "C" void kernel_launch(void* const* d_in, const int* in_sizes, int n_in,
                              void* d_out, int out_size, void* d_ws,
                              size_t ws_size, hipStream_t stream) {
  const float* hidden = (const float*)d_in[0];
  const int* hashidx = (const int*)d_in[1];
  const float* emb = (const float*)d_in[2];
  const float* w_v = (const float*)d_in[3];
  const float* w_k = (const float*)d_in[4];
  const float* g_h = (const float*)d_in[5];
  const float* g_k = (const float*)d_in[6];
  const float* g_v = (const float*)d_in[7];
  const float* conv_w = (const float*)d_in[8];
  const float* conv_b = (const float*)d_in[9];
  float* out = (float*)d_out;

  char* w = (char*)d_ws;
  bf16* e16 = (bf16*)w;  w += (size_t)MROWS * EDIM * 2;   // 33.5 MB
  bf16* wv16 = (bf16*)w; w += (size_t)HDIM * EDIM * 2;    // 5.2 MB
  bf16* wk16 = (bf16*)w; w += (size_t)HDIM * EDIM * 2;    // 5.2 MB
  bf16* vt16 = (bf16*)w; w += (size_t)MROWS * HDIM * 2;   // 83.9 MB
  bf16* kt16 = (bf16*)w; w += (size_t)MROWS * HDIM * 2;   // 83.9 MB (-> v_tilde)
  bf16* vn16 = (bf16*)w; w += (size_t)MROWS * HDIM * 2;   // 83.9 MB

  k_gather<<<MROWS, 256, 0, stream>>>(hashidx, emb, e16);
  k_cvt<<<(HDIM * EDIM) / 2048, 256, 0, stream>>>(w_v, wv16, HDIM * EDIM);
  k_cvt<<<(HDIM * EDIM) / 2048, 256, 0, stream>>>(w_k, wk16, HDIM * EDIM);
  k_gemm<<<dim3((2 * HDIM) / BN, MROWS / BM), 256, 0, stream>>>(e16, wv16, wk16,
                                                                vt16, kt16);
  k_gate<<<MROWS, 320, 0, stream>>>(hidden, kt16, vt16, g_h, g_k, g_v, vn16);
  k_conv<<<MROWS, 320, 0, stream>>>(hidden, vn16, kt16, conv_w, conv_b, out);
}

// Round 2
// 485.859 us; speedup vs baseline: 1.1322x; 1.1322x over previous
//
#include <hip/hip_runtime.h>
#include <cstddef>
#include <cstdint>

typedef __bf16 bf16;
typedef __bf16 bf16x4 __attribute__((ext_vector_type(4)));
typedef __bf16 bf16x8 __attribute__((ext_vector_type(8)));
typedef float f32x4 __attribute__((ext_vector_type(4)));

#define AS1C(p) ((const __attribute__((address_space(1))) void*)(p))
#define AS3(p)  ((__attribute__((address_space(3))) void*)(p))

#define MROWS 16384
#define HDIM 2560
#define EDIM 1024
#define LSEQ 4096

static __device__ const int kHeadOff[8] = {0, 250007, 500020, 750047,
                                           1000078, 1250115, 1500158, 1750207};

// ---------------- K1: gather emb rows -> bf16 E [MROWS][1024] ----------------
__global__ __launch_bounds__(256) void k_gather(const int* __restrict__ hidx,
                                                const float* __restrict__ emb,
                                                bf16* __restrict__ E) {
  const int m = blockIdx.x;
  const int t = threadIdx.x;
  const int head = t >> 5;          // 8 heads x 32 threads
  const int e4 = (t & 31) * 4;      // 4 floats per thread
  const int rid = hidx[m * 8 + head] + kHeadOff[head];
  const float4 v = *(const float4*)(emb + (size_t)rid * 128 + e4);
  bf16x4 o;
  o[0] = (bf16)v.x; o[1] = (bf16)v.y; o[2] = (bf16)v.z; o[3] = (bf16)v.w;
  *(bf16x4*)(E + (size_t)m * EDIM + head * 128 + e4) = o;
}

// ---------------- fp32 -> bf16 bulk convert (weights) ----------------
__global__ __launch_bounds__(256) void k_cvt(const float* __restrict__ src,
                                             bf16* __restrict__ dst, int n) {
  int i = (blockIdx.x * 256 + threadIdx.x) * 8;
  if (i + 8 > n) return;
  float4 a = *(const float4*)(src + i);
  float4 b = *(const float4*)(src + i + 4);
  bf16x8 o;
  o[0] = (bf16)a.x; o[1] = (bf16)a.y; o[2] = (bf16)a.z; o[3] = (bf16)a.w;
  o[4] = (bf16)b.x; o[5] = (bf16)b.y; o[6] = (bf16)b.z; o[7] = (bf16)b.w;
  *(bf16x8*)(dst + i) = o;
}

// reduce across the 16 lanes of each khalf group (lane = khalf*16 + r16)
__device__ __forceinline__ float red16(float v) {
  v += __shfl_xor(v, 1);
  v += __shfl_xor(v, 2);
  v += __shfl_xor(v, 4);
  v += __shfl_xor(v, 8);
  return v;
}

// ---------------- K2: GEMM over concat(Wv,Wk) with fused epilogue -----------
// vt blocks: store Vt bf16, atomic S4 = sum v^2
// kt blocks: NO store; atomic S1 = sum h^2, S2 = sum h*gh*gk*k, S3 = sum k^2
// S layout: S[m*4 + {0:h2, 1:hk, 2:k2, 3:v2}]
#define BM 128
#define BN 128
#define BK 32

__global__ __launch_bounds__(256) void k_gemm(const bf16* __restrict__ A,
                                              const bf16* __restrict__ Wv,
                                              const bf16* __restrict__ Wk,
                                              const float* __restrict__ hidden,
                                              const float* __restrict__ g_h,
                                              const float* __restrict__ g_k,
                                              bf16* __restrict__ Vt,
                                              float* __restrict__ S) {
  __shared__ __attribute__((aligned(16))) bf16 lA[BM * BK];  // 8 KB
  __shared__ __attribute__((aligned(16))) bf16 lB[BN * BK];  // 8 KB

  const int tid = threadIdx.x;
  const int wave = tid >> 6, lane = tid & 63;
  const int wm = wave >> 1, wn = wave & 1;
  const int m0 = blockIdx.y * BM;
  int n0 = blockIdx.x * BN;            // 0..5119 over concat(v,k)
  const bool isV = (n0 < HDIM);
  const bf16* W;
  if (isV) { W = Wv; } else { W = Wk; n0 -= HDIM; }

  f32x4 acc[4][4] = {};

  const int r16 = lane & 15;
  const int khalf = lane >> 4;         // 0..3
  const int kOffE = khalf * 8;         // k element offset of this lane's frag

  // staging geometry: chunk lin = iss*256 + tid covers 16B; row=lin>>2, c8=(lin&3)*8
  const int srow = tid >> 2;
  const int sc8 = (tid & 3) * 8;

  for (int k0 = 0; k0 < EDIM; k0 += BK) {
    __syncthreads();  // previous iter's LDS reads done before overwrite
#pragma unroll
    for (int iss = 0; iss < 2; ++iss) {
      const int row = iss * 64 + srow;
      const bf16* ga = A + (size_t)(m0 + row) * EDIM + k0 + sc8;
      __builtin_amdgcn_global_load_lds(AS1C(ga),
          AS3((char*)lA + iss * 4096 + wave * 1024), 16, 0, 0);
      const bf16* gb = W + (size_t)(n0 + row) * EDIM + k0 + sc8;
      __builtin_amdgcn_global_load_lds(AS1C(gb),
          AS3((char*)lB + iss * 4096 + wave * 1024), 16, 0, 0);
    }
    __syncthreads();  // compiler drains vmcnt before barrier -> data visible

    bf16x8 aF[4], bF[4];
#pragma unroll
    for (int mi = 0; mi < 4; ++mi)
      aF[mi] = *(const bf16x8*)&lA[(wm * 64 + mi * 16 + r16) * BK + kOffE];
#pragma unroll
    for (int nj = 0; nj < 4; ++nj)
      bF[nj] = *(const bf16x8*)&lB[(wn * 64 + nj * 16 + r16) * BK + kOffE];
#pragma unroll
    for (int mi = 0; mi < 4; ++mi)
#pragma unroll
      for (int nj = 0; nj < 4; ++nj)
        acc[mi][nj] = __builtin_amdgcn_mfma_f32_16x16x32_bf16(
            aF[mi], bF[nj], acc[mi][nj], 0, 0, 0);
  }

  // epilogue. C/D frag mapping: col = lane&15 (+nj*16), row = khalf*4 + r (+mi*16)
  if (isV) {
#pragma unroll
    for (int mi = 0; mi < 4; ++mi) {
#pragma unroll
      for (int nj = 0; nj < 4; ++nj) {
        const int col = n0 + wn * 64 + nj * 16 + r16;
#pragma unroll
        for (int r = 0; r < 4; ++r) {
          const int row = m0 + wm * 64 + mi * 16 + khalf * 4 + r;
          Vt[(size_t)row * HDIM + col] = (bf16)acc[mi][nj][r];
        }
      }
#pragma unroll
      for (int r = 0; r < 4; ++r) {
        float p = 0.f;
#pragma unroll
        for (int nj = 0; nj < 4; ++nj) p += acc[mi][nj][r] * acc[mi][nj][r];
        p = red16(p);
        if (r16 == 0) {
          const int row = m0 + wm * 64 + mi * 16 + khalf * 4 + r;
          atomicAdd(&S[(size_t)row * 4 + 3], p);
        }
      }
    }
  } else {
    float ghk[4];
#pragma unroll
    for (int nj = 0; nj < 4; ++nj) {
      const int col = n0 + wn * 64 + nj * 16 + r16;
      ghk[nj] = g_h[col] * g_k[col];
    }
#pragma unroll
    for (int mi = 0; mi < 4; ++mi) {
#pragma unroll
      for (int r = 0; r < 4; ++r) {
        const int row = m0 + wm * 64 + mi * 16 + khalf * 4 + r;
        float p1 = 0.f, p2 = 0.f, p3 = 0.f;
#pragma unroll
        for (int nj = 0; nj < 4; ++nj) {
          const int col = n0 + wn * 64 + nj * 16 + r16;
          const float k = acc[mi][nj][r];
          const float h = hidden[(size_t)row * HDIM + col];
          p1 += h * h;
          p2 += h * ghk[nj] * k;
          p3 += k * k;
        }
        p1 = red16(p1); p2 = red16(p2); p3 = red16(p3);
        if (r16 == 0) {
          float* Sr = S + (size_t)row * 4;
          atomicAdd(Sr + 0, p1);
          atomicAdd(Sr + 1, p2);
          atomicAdd(Sr + 2, p3);
        }
      }
    }
  }
}

// ---------------- K3: per-row scalars -> (alpha, alpha*inv_v) ----------------
__global__ __launch_bounds__(256) void k_scal(const float* __restrict__ S,
                                              float* __restrict__ AB) {
  const int m = blockIdx.x * 256 + threadIdx.x;
  const float s1 = S[(size_t)m * 4 + 0];
  const float s2 = S[(size_t)m * 4 + 1];
  const float s3 = S[(size_t)m * 4 + 2];
  const float s4 = S[(size_t)m * 4 + 3];
  const float inv_h = rsqrtf(s1 * (1.f / HDIM) + 1e-6f);
  const float inv_k = rsqrtf(s3 * (1.f / HDIM) + 1e-6f);
  const float dot = s2 * inv_h * inv_k * 0.019764235f;  // 1/sqrt(2560)
  float st = sqrtf(fmaxf(fabsf(dot), 1e-6f));
  st = (dot < 0.f) ? -st : st;
  if (dot == 0.f) st = 0.f;
  const float alpha = 1.f / (1.f + __expf(-st));
  const float inv_v = rsqrtf(alpha * alpha * s4 * (1.f / HDIM) + 1e-6f);
  AB[(size_t)m * 2 + 0] = alpha;
  AB[(size_t)m * 2 + 1] = alpha * inv_v;
}

// ---------------- K4: fused v_tilde/v_n recompute + conv + SiLU + residuals --
// block: 8 consecutive l rows (one b), full H. Rolling 4-row v_n window, fully
// unrolled (static indices; rule #20).
__global__ __launch_bounds__(320) void k_fuse(const float* __restrict__ hidden,
                                              const bf16* __restrict__ Vt,
                                              const float* __restrict__ AB,
                                              const float* __restrict__ g_v,
                                              const float* __restrict__ conv_w,
                                              const float* __restrict__ conv_b,
                                              float* __restrict__ out) {
  const int mbase = blockIdx.x * 8;
  const int l0 = mbase & (LSEQ - 1);
  const int t = threadIdx.x;
  const int h0 = t * 8;

  float gv[8], cb[8];
  *(float4*)&gv[0] = *(const float4*)(g_v + h0);
  *(float4*)&gv[4] = *(const float4*)(g_v + h0 + 4);
  *(float4*)&cb[0] = *(const float4*)(conv_b + h0);
  *(float4*)&cb[4] = *(const float4*)(conv_b + h0 + 4);
  float4 cw[8];
#pragma unroll
  for (int i = 0; i < 8; ++i)
    cw[i] = *(const float4*)(conv_w + (size_t)(h0 + i) * 4);

  float win[4][8];
#pragma unroll
  for (int jj = 0; jj < 4; ++jj)
#pragma unroll
    for (int i = 0; i < 8; ++i) win[jj][i] = 0.f;

#pragma unroll
  for (int j = 0; j < 11; ++j) {  // source rows mbase-3 .. mbase+7
    const int lj = l0 - 3 + j;
    const int m = mbase - 3 + j;
    float vtl[8];
    if (lj >= 0) {
      const float alpha = AB[(size_t)m * 2 + 0];
      const float av = AB[(size_t)m * 2 + 1];
      const bf16x8 v = *(const bf16x8*)(Vt + (size_t)m * HDIM + h0);
#pragma unroll
      for (int i = 0; i < 8; ++i) {
        const float vt = (float)v[i];
        vtl[i] = alpha * vt;
        win[j & 3][i] = av * vt * gv[i];  // v_n
      }
    } else {
#pragma unroll
      for (int i = 0; i < 8; ++i) { win[j & 3][i] = 0.f; vtl[i] = 0.f; }
    }
    if (j >= 3) {
      const int R = mbase + j - 3;
      const size_t base = (size_t)R * HDIM + h0;
      float hx[8];
      *(float4*)&hx[0] = *(const float4*)(hidden + base);
      *(float4*)&hx[4] = *(const float4*)(hidden + base + 4);
      float o[8];
#pragma unroll
      for (int i = 0; i < 8; ++i) {
        float c = cb[i];
        c += ((const float*)&cw[i])[0] * win[(j - 3) & 3][i];
        c += ((const float*)&cw[i])[1] * win[(j - 2) & 3][i];
        c += ((const float*)&cw[i])[2] * win[(j - 1) & 3][i];
        c += ((const float*)&cw[i])[3] * win[j & 3][i];
        const float y = c / (1.f + __expf(-c));  // silu
        o[i] = hx[i] + y + vtl[i];
      }
      *(float4*)(out + base) = *(float4*)&o[0];
      *(float4*)(out + base + 4) = *(float4*)&o[4];
    }
  }
}

// ---------------- launcher ----------------
extern "C" void kernel_launch(void* const* d_in, const int* in_sizes, int n_in,
                              void* d_out, int out_size, void* d_ws,
                              size_t ws_size, hipStream_t stream) {
  const float* hidden = (const float*)d_in[0];
  const int* hashidx = (const int*)d_in[1];
  const float* emb = (const float*)d_in[2];
  const float* w_v = (const float*)d_in[3];
  const float* w_k = (const float*)d_in[4];
  const float* g_h = (const float*)d_in[5];
  const float* g_k = (const float*)d_in[6];
  const float* g_v = (const float*)d_in[7];
  const float* conv_w = (const float*)d_in[8];
  const float* conv_b = (const float*)d_in[9];
  float* out = (float*)d_out;

  char* w = (char*)d_ws;
  bf16* e16 = (bf16*)w;  w += (size_t)MROWS * EDIM * 2;   // 33.5 MB
  bf16* wv16 = (bf16*)w; w += (size_t)HDIM * EDIM * 2;    // 5.2 MB
  bf16* wk16 = (bf16*)w; w += (size_t)HDIM * EDIM * 2;    // 5.2 MB
  bf16* vt16 = (bf16*)w; w += (size_t)MROWS * HDIM * 2;   // 83.9 MB
  float* S = (float*)w;  w += (size_t)MROWS * 4 * 4;      // 256 KB
  float* AB = (float*)w; w += (size_t)MROWS * 2 * 4;      // 128 KB

  hipMemsetAsync(S, 0, (size_t)MROWS * 4 * 4, stream);
  k_gather<<<MROWS, 256, 0, stream>>>(hashidx, emb, e16);
  k_cvt<<<(HDIM * EDIM) / 2048, 256, 0, stream>>>(w_v, wv16, HDIM * EDIM);
  k_cvt<<<(HDIM * EDIM) / 2048, 256, 0, stream>>>(w_k, wk16, HDIM * EDIM);
  k_gemm<<<dim3((2 * HDIM) / BN, MROWS / BM), 256, 0, stream>>>(
      e16, wv16, wk16, hidden, g_h, g_k, vt16, S);
  k_scal<<<MROWS / 256, 256, 0, stream>>>(S, AB);
  k_fuse<<<MROWS / 8, 320, 0, stream>>>(hidden, vt16, AB, g_v, conv_w, conv_b,
                                        out);
}

// Round 3
// 485.003 us; speedup vs baseline: 1.1342x; 1.0018x over previous
//
#include <hip/hip_runtime.h>
#include <cstddef>
#include <cstdint>

typedef __bf16 bf16;
typedef __bf16 bf16x4 __attribute__((ext_vector_type(4)));
typedef __bf16 bf16x8 __attribute__((ext_vector_type(8)));
typedef float f32x4 __attribute__((ext_vector_type(4)));

#define AS1C(p) ((const __attribute__((address_space(1))) void*)(p))
#define AS3(p)  ((__attribute__((address_space(3))) void*)(p))

#define MROWS 16384
#define HDIM 2560
#define EDIM 1024
#define LSEQ 4096

static __device__ const int kHeadOff[8] = {0, 250007, 500020, 750047,
                                           1000078, 1250115, 1500158, 1750207};

// ---------------- K1: gather emb rows -> bf16 E [MROWS][1024] ----------------
__global__ __launch_bounds__(256) void k_gather(const int* __restrict__ hidx,
                                                const float* __restrict__ emb,
                                                bf16* __restrict__ E) {
  const int m = blockIdx.x;
  const int t = threadIdx.x;
  const int head = t >> 5;          // 8 heads x 32 threads
  const int e4 = (t & 31) * 4;      // 4 floats per thread
  const int rid = hidx[m * 8 + head] + kHeadOff[head];
  const float4 v = *(const float4*)(emb + (size_t)rid * 128 + e4);
  bf16x4 o;
  o[0] = (bf16)v.x; o[1] = (bf16)v.y; o[2] = (bf16)v.z; o[3] = (bf16)v.w;
  *(bf16x4*)(E + (size_t)m * EDIM + head * 128 + e4) = o;
}

// ---------------- fp32 -> bf16 bulk convert (weights) ----------------
__global__ __launch_bounds__(256) void k_cvt(const float* __restrict__ src,
                                             bf16* __restrict__ dst, int n) {
  int i = (blockIdx.x * 256 + threadIdx.x) * 8;
  if (i + 8 > n) return;
  float4 a = *(const float4*)(src + i);
  float4 b = *(const float4*)(src + i + 4);
  bf16x8 o;
  o[0] = (bf16)a.x; o[1] = (bf16)a.y; o[2] = (bf16)a.z; o[3] = (bf16)a.w;
  o[4] = (bf16)b.x; o[5] = (bf16)b.y; o[6] = (bf16)b.z; o[7] = (bf16)b.w;
  *(bf16x8*)(dst + i) = o;
}

// reduce across the 16 lanes of each khalf group (lane = khalf*16 + r16)
__device__ __forceinline__ float red16(float v) {
  v += __shfl_xor(v, 1);
  v += __shfl_xor(v, 2);
  v += __shfl_xor(v, 4);
  v += __shfl_xor(v, 8);
  return v;
}

// ================= K2: 256x256 8-phase GEMM (T2+T3+T4+T5) ===================
// C[m][n] = sum_k A[m][k] * W[n][k];  A=[16384][1024], W=[2560][1024]
// 512 thr = 8 waves (2M x 4N); per-wave out 128x64; BK=64 (2x k=32 MFMA).
// LDS: 2 buffers x (A 32KB + B 32KB), row-major [256 rows][64 cols] bf16,
// XOR-swizzle byte ^= (row&7)<<4 (involution, both staging-source and read).
// B rows permuted: LDS_row = (njhalf)*128 + wn*32 + (row&31) so each stage
// unit (8KB = 64 LDS rows) is contiguous. Stage unit = 1 gload_lds/thread.
// vt blocks: store Vt bf16 + atomic S4; kt blocks: no store, atomic S1,S2,S3.

__device__ __forceinline__ void stA(const bf16* __restrict__ A, char* ldsc,
                                    int bufo, int q, int m0, int k0, int tid,
                                    int arow, int acolb) {
  const bf16* src = A + (size_t)(m0 + q * 64 + arow) * EDIM + k0 + (acolb >> 1);
  __builtin_amdgcn_global_load_lds(AS1C(src),
      AS3(ldsc + bufo + q * 8192 + (tid >> 6) * 1024), 16, 0, 0);
}

__device__ __forceinline__ void stB(const bf16* __restrict__ W, char* ldsc,
                                    int bufo, int u, int n0, int k0, int tid,
                                    int arow, int acolb) {
  const int L = u * 64 + arow;                       // LDS row (permuted space)
  const int wrow = ((L >> 5) & 3) * 64 + (L >> 7) * 32 + (L & 31);
  const bf16* src = W + (size_t)(n0 + wrow) * EDIM + k0 + (acolb >> 1);
  __builtin_amdgcn_global_load_lds(AS1C(src),
      AS3(ldsc + bufo + 32768 + u * 8192 + (tid >> 6) * 1024), 16, 0, 0);
}

#define RDA(BUFO, MIB) do { \
  _Pragma("unroll") for (int mi = 0; mi < 4; ++mi) { \
    a[mi][0] = *(const bf16x8*)(ldsc + (BUFO) + aBase + ((MIB) + mi) * 2048 + c0); \
    a[mi][1] = *(const bf16x8*)(ldsc + (BUFO) + aBase + ((MIB) + mi) * 2048 + (c0 ^ 64)); \
  } } while (0)

#define RDB(BUFO, DST, NJB) do { \
  _Pragma("unroll") for (int nj = 0; nj < 2; ++nj) { \
    DST[nj][0] = *(const bf16x8*)(ldsc + (BUFO) + bRowOff[(NJB) + nj] + c0); \
    DST[nj][1] = *(const bf16x8*)(ldsc + (BUFO) + bRowOff[(NJB) + nj] + (c0 ^ 64)); \
  } } while (0)

#define MFMAQ(MIOFF, NJOFF, BARR) do { \
  _Pragma("unroll") for (int mi = 0; mi < 4; ++mi) { \
    _Pragma("unroll") for (int nj = 0; nj < 2; ++nj) { \
      acc[(MIOFF) + mi][(NJOFF) + nj] = __builtin_amdgcn_mfma_f32_16x16x32_bf16( \
          a[mi][0], BARR[nj][0], acc[(MIOFF) + mi][(NJOFF) + nj], 0, 0, 0); \
      acc[(MIOFF) + mi][(NJOFF) + nj] = __builtin_amdgcn_mfma_f32_16x16x32_bf16( \
          a[mi][1], BARR[nj][1], acc[(MIOFF) + mi][(NJOFF) + nj], 0, 0, 0); \
    } } } while (0)

#define MID_SYNC() do { __builtin_amdgcn_s_barrier(); \
  asm volatile("s_waitcnt lgkmcnt(0)" ::: "memory"); \
  __builtin_amdgcn_sched_barrier(0); \
  __builtin_amdgcn_s_setprio(1); } while (0)

#define END_PHASE() do { __builtin_amdgcn_s_setprio(0); \
  __builtin_amdgcn_s_barrier(); } while (0)

#define VMCNT6() asm volatile("s_waitcnt vmcnt(6)" ::: "memory")
#define VMCNT0() asm volatile("s_waitcnt vmcnt(0)" ::: "memory")

__global__ __launch_bounds__(512) void k_gemm(const bf16* __restrict__ A,
                                              const bf16* __restrict__ Wv,
                                              const bf16* __restrict__ Wk,
                                              const float* __restrict__ hidden,
                                              const float* __restrict__ g_h,
                                              const float* __restrict__ g_k,
                                              bf16* __restrict__ Vt,
                                              float* __restrict__ S) {
  __shared__ __attribute__((aligned(128))) char ldsc[131072];
  const int tid = threadIdx.x;
  const int wid = tid >> 6, lane = tid & 63;
  const int wm = wid >> 2, wn = wid & 3;
  const int r16 = lane & 15, khalf = lane >> 4;
  const int m0 = blockIdx.y * 256;
  const int gx = blockIdx.x;
  const bool isV = (gx < 10);
  const int n0 = (isV ? gx : gx - 10) * 256;
  const bf16* W = isV ? Wv : Wk;

  const int BUF0 = 0, BUF1 = 65536;
  const int flip = (r16 & 7) << 4;
  const int c0 = (khalf * 16) ^ flip;
  const int aBase = (wm * 128 + r16) * 128;
  int bRowOff[4];
#pragma unroll
  for (int nj = 0; nj < 4; ++nj)
    bRowOff[nj] = ((nj >> 1) * 128 + wn * 32 + (nj & 1) * 16 + r16) * 128 + 32768;

  // staging per-thread geometry (identical for all units)
  const int arow = tid >> 3;                       // 0..63 row within unit
  const int acolb = ((tid & 7) * 16) ^ ((arow & 7) << 4);  // swizzled colbyte

  f32x4 acc[8][4] = {};
  bf16x8 a[4][2], bl[2][2], bh[2][2];

  // ---- prologue: tile0 (buf0,k=0) full; tile1 (buf1,k=64) A-lo,B-lo,B-hi ----
  stA(A, ldsc, BUF0, 0, m0, 0, tid, arow, acolb);
  stA(A, ldsc, BUF0, 2, m0, 0, tid, arow, acolb);
  stB(W, ldsc, BUF0, 0, n0, 0, tid, arow, acolb);
  stB(W, ldsc, BUF0, 1, n0, 0, tid, arow, acolb);
  stB(W, ldsc, BUF0, 2, n0, 0, tid, arow, acolb);
  stB(W, ldsc, BUF0, 3, n0, 0, tid, arow, acolb);
  stA(A, ldsc, BUF0, 1, m0, 0, tid, arow, acolb);
  stA(A, ldsc, BUF0, 3, m0, 0, tid, arow, acolb);
  stA(A, ldsc, BUF1, 0, m0, 64, tid, arow, acolb);
  stA(A, ldsc, BUF1, 2, m0, 64, tid, arow, acolb);
  stB(W, ldsc, BUF1, 0, n0, 64, tid, arow, acolb);
  stB(W, ldsc, BUF1, 1, n0, 64, tid, arow, acolb);
  stB(W, ldsc, BUF1, 2, n0, 64, tid, arow, acolb);
  stB(W, ldsc, BUF1, 3, n0, 64, tid, arow, acolb);
  VMCNT6();                       // tile0 (oldest 8 loads) landed
  __builtin_amdgcn_s_barrier();

  for (int it = 0; it < 8; ++it) {
    const int kO = it * 128 + 64;       // odd tile of this iter (buf1)
    const int kN = it * 128 + 128;      // next even tile (buf0)
    const int kN1 = kN + 64;            // next odd tile (buf1)
    const bool pf = (it < 7);

    // ph1: even tile, quad(mi0-3, nj0-1); stage A-hi(odd tile, buf1)
    RDA(BUF0, 0);
    RDB(BUF0, bl, 0);
    stA(A, ldsc, BUF1, 1, m0, kO, tid, arow, acolb);
    stA(A, ldsc, BUF1, 3, m0, kO, tid, arow, acolb);
    MID_SYNC();
    MFMAQ(0, 0, bl);
    END_PHASE();

    // ph2: quad(mi0-3, nj2-3); stage A-lo(next even, buf0)
    RDB(BUF0, bh, 2);
    if (pf) {
      stA(A, ldsc, BUF0, 0, m0, kN, tid, arow, acolb);
      stA(A, ldsc, BUF0, 2, m0, kN, tid, arow, acolb);
    }
    MID_SYNC();
    MFMAQ(0, 2, bh);
    END_PHASE();

    // ph3: quad(mi4-7, nj0-1); stage B-lo(next even)
    RDA(BUF0, 4);
    if (pf) {
      stB(W, ldsc, BUF0, 0, n0, kN, tid, arow, acolb);
      stB(W, ldsc, BUF0, 1, n0, kN, tid, arow, acolb);
    }
    MID_SYNC();
    MFMAQ(4, 0, bl);
    END_PHASE();

    // ph4: quad(mi4-7, nj2-3); stage B-hi(next even); vmcnt
    if (pf) {
      stB(W, ldsc, BUF0, 2, n0, kN, tid, arow, acolb);
      stB(W, ldsc, BUF0, 3, n0, kN, tid, arow, acolb);
      VMCNT6();                   // odd tile of this iter fully landed
    } else {
      VMCNT0();                   // tail: exact counts drift, drain once
    }
    MID_SYNC();
    MFMAQ(4, 2, bh);
    END_PHASE();

    // ph5: odd tile, quad(mi0-3, nj0-1); stage A-hi(next even, buf0)
    RDA(BUF1, 0);
    RDB(BUF1, bl, 0);
    if (pf) {
      stA(A, ldsc, BUF0, 1, m0, kN, tid, arow, acolb);
      stA(A, ldsc, BUF0, 3, m0, kN, tid, arow, acolb);
    }
    MID_SYNC();
    MFMAQ(0, 0, bl);
    END_PHASE();

    // ph6: quad(mi0-3, nj2-3); stage A-lo(next odd, buf1)
    RDB(BUF1, bh, 2);
    if (pf) {
      stA(A, ldsc, BUF1, 0, m0, kN1, tid, arow, acolb);
      stA(A, ldsc, BUF1, 2, m0, kN1, tid, arow, acolb);
    }
    MID_SYNC();
    MFMAQ(0, 2, bh);
    END_PHASE();

    // ph7: quad(mi4-7, nj0-1); stage B-lo(next odd)
    RDA(BUF1, 4);
    if (pf) {
      stB(W, ldsc, BUF1, 0, n0, kN1, tid, arow, acolb);
      stB(W, ldsc, BUF1, 1, n0, kN1, tid, arow, acolb);
    }
    MID_SYNC();
    MFMAQ(4, 0, bl);
    END_PHASE();

    // ph8: quad(mi4-7, nj2-3); stage B-hi(next odd); vmcnt
    if (pf) {
      stB(W, ldsc, BUF1, 2, n0, kN1, tid, arow, acolb);
      stB(W, ldsc, BUF1, 3, n0, kN1, tid, arow, acolb);
    }
    VMCNT6();                     // next even tile fully landed
    MID_SYNC();
    MFMAQ(4, 2, bh);
    END_PHASE();
  }

  // ---- epilogue: row = m0+wm*128+mi*16+khalf*4+r; col = n0+wn*64+nj*16+r16
  if (isV) {
#pragma unroll
    for (int mi = 0; mi < 8; ++mi) {
#pragma unroll
      for (int nj = 0; nj < 4; ++nj) {
        const int col = n0 + wn * 64 + nj * 16 + r16;
#pragma unroll
        for (int r = 0; r < 4; ++r) {
          const int row = m0 + wm * 128 + mi * 16 + khalf * 4 + r;
          Vt[(size_t)row * HDIM + col] = (bf16)acc[mi][nj][r];
        }
      }
#pragma unroll
      for (int r = 0; r < 4; ++r) {
        float p = 0.f;
#pragma unroll
        for (int nj = 0; nj < 4; ++nj) p += acc[mi][nj][r] * acc[mi][nj][r];
        p = red16(p);
        if (r16 == 0) {
          const int row = m0 + wm * 128 + mi * 16 + khalf * 4 + r;
          atomicAdd(&S[(size_t)row * 4 + 3], p);
        }
      }
    }
  } else {
    float ghk[4];
#pragma unroll
    for (int nj = 0; nj < 4; ++nj) {
      const int col = n0 + wn * 64 + nj * 16 + r16;
      ghk[nj] = g_h[col] * g_k[col];
    }
#pragma unroll
    for (int mi = 0; mi < 8; ++mi) {
#pragma unroll
      for (int r = 0; r < 4; ++r) {
        const int row = m0 + wm * 128 + mi * 16 + khalf * 4 + r;
        float p1 = 0.f, p2 = 0.f, p3 = 0.f;
#pragma unroll
        for (int nj = 0; nj < 4; ++nj) {
          const int col = n0 + wn * 64 + nj * 16 + r16;
          const float k = acc[mi][nj][r];
          const float h = hidden[(size_t)row * HDIM + col];
          p1 += h * h;
          p2 += h * ghk[nj] * k;
          p3 += k * k;
        }
        p1 = red16(p1); p2 = red16(p2); p3 = red16(p3);
        if (r16 == 0) {
          float* Sr = S + (size_t)row * 4;
          atomicAdd(Sr + 0, p1);
          atomicAdd(Sr + 1, p2);
          atomicAdd(Sr + 2, p3);
        }
      }
    }
  }
}

// ---------------- K3: per-row scalars -> (alpha, alpha*inv_v) ----------------
__global__ __launch_bounds__(256) void k_scal(const float* __restrict__ S,
                                              float* __restrict__ AB) {
  const int m = blockIdx.x * 256 + threadIdx.x;
  const float s1 = S[(size_t)m * 4 + 0];
  const float s2 = S[(size_t)m * 4 + 1];
  const float s3 = S[(size_t)m * 4 + 2];
  const float s4 = S[(size_t)m * 4 + 3];
  const float inv_h = rsqrtf(s1 * (1.f / HDIM) + 1e-6f);
  const float inv_k = rsqrtf(s3 * (1.f / HDIM) + 1e-6f);
  const float dot = s2 * inv_h * inv_k * 0.019764235f;  // 1/sqrt(2560)
  float st = sqrtf(fmaxf(fabsf(dot), 1e-6f));
  st = (dot < 0.f) ? -st : st;
  if (dot == 0.f) st = 0.f;
  const float alpha = 1.f / (1.f + __expf(-st));
  const float inv_v = rsqrtf(alpha * alpha * s4 * (1.f / HDIM) + 1e-6f);
  AB[(size_t)m * 2 + 0] = alpha;
  AB[(size_t)m * 2 + 1] = alpha * inv_v;
}

// ---------------- K4: fused v_tilde/v_n recompute + conv + SiLU + residuals --
__global__ __launch_bounds__(320) void k_fuse(const float* __restrict__ hidden,
                                              const bf16* __restrict__ Vt,
                                              const float* __restrict__ AB,
                                              const float* __restrict__ g_v,
                                              const float* __restrict__ conv_w,
                                              const float* __restrict__ conv_b,
                                              float* __restrict__ out) {
  const int mbase = blockIdx.x * 8;
  const int l0 = mbase & (LSEQ - 1);
  const int t = threadIdx.x;
  const int h0 = t * 8;

  float gv[8], cb[8];
  *(float4*)&gv[0] = *(const float4*)(g_v + h0);
  *(float4*)&gv[4] = *(const float4*)(g_v + h0 + 4);
  *(float4*)&cb[0] = *(const float4*)(conv_b + h0);
  *(float4*)&cb[4] = *(const float4*)(conv_b + h0 + 4);
  float4 cw[8];
#pragma unroll
  for (int i = 0; i < 8; ++i)
    cw[i] = *(const float4*)(conv_w + (size_t)(h0 + i) * 4);

  float win[4][8];
#pragma unroll
  for (int jj = 0; jj < 4; ++jj)
#pragma unroll
    for (int i = 0; i < 8; ++i) win[jj][i] = 0.f;

#pragma unroll
  for (int j = 0; j < 11; ++j) {  // source rows mbase-3 .. mbase+7
    const int lj = l0 - 3 + j;
    const int m = mbase - 3 + j;
    float vtl[8];
    if (lj >= 0) {
      const float alpha = AB[(size_t)m * 2 + 0];
      const float av = AB[(size_t)m * 2 + 1];
      const bf16x8 v = *(const bf16x8*)(Vt + (size_t)m * HDIM + h0);
#pragma unroll
      for (int i = 0; i < 8; ++i) {
        const float vt = (float)v[i];
        vtl[i] = alpha * vt;
        win[j & 3][i] = av * vt * gv[i];  // v_n
      }
    } else {
#pragma unroll
      for (int i = 0; i < 8; ++i) { win[j & 3][i] = 0.f; vtl[i] = 0.f; }
    }
    if (j >= 3) {
      const int R = mbase + j - 3;
      const size_t base = (size_t)R * HDIM + h0;
      float hx[8];
      *(float4*)&hx[0] = *(const float4*)(hidden + base);
      *(float4*)&hx[4] = *(const float4*)(hidden + base + 4);
      float o[8];
#pragma unroll
      for (int i = 0; i < 8; ++i) {
        float c = cb[i];
        c += ((const float*)&cw[i])[0] * win[(j - 3) & 3][i];
        c += ((const float*)&cw[i])[1] * win[(j - 2) & 3][i];
        c += ((const float*)&cw[i])[2] * win[(j - 1) & 3][i];
        c += ((const float*)&cw[i])[3] * win[j & 3][i];
        const float y = c / (1.f + __expf(-c));  // silu
        o[i] = hx[i] + y + vtl[i];
      }
      *(float4*)(out + base) = *(float4*)&o[0];
      *(float4*)(out + base + 4) = *(float4*)&o[4];
    }
  }
}

// ---------------- launcher ----------------
extern "C" void kernel_launch(void* const* d_in, const int* in_sizes, int n_in,
                              void* d_out, int out_size, void* d_ws,
                              size_t ws_size, hipStream_t stream) {
  const float* hidden = (const float*)d_in[0];
  const int* hashidx = (const int*)d_in[1];
  const float* emb = (const float*)d_in[2];
  const float* w_v = (const float*)d_in[3];
  const float* w_k = (const float*)d_in[4];
  const float* g_h = (const float*)d_in[5];
  const float* g_k = (const float*)d_in[6];
  const float* g_v = (const float*)d_in[7];
  const float* conv_w = (const float*)d_in[8];
  const float* conv_b = (const float*)d_in[9];
  float* out = (float*)d_out;

  char* w = (char*)d_ws;
  bf16* e16 = (bf16*)w;  w += (size_t)MROWS * EDIM * 2;   // 33.5 MB
  bf16* wv16 = (bf16*)w; w += (size_t)HDIM * EDIM * 2;    // 5.2 MB
  bf16* wk16 = (bf16*)w; w += (size_t)HDIM * EDIM * 2;    // 5.2 MB
  bf16* vt16 = (bf16*)w; w += (size_t)MROWS * HDIM * 2;   // 83.9 MB
  float* S = (float*)w;  w += (size_t)MROWS * 4 * 4;      // 256 KB
  float* AB = (float*)w; w += (size_t)MROWS * 2 * 4;      // 128 KB

  hipMemsetAsync(S, 0, (size_t)MROWS * 4 * 4, stream);
  k_gather<<<MROWS, 256, 0, stream>>>(hashidx, emb, e16);
  k_cvt<<<(HDIM * EDIM) / 2048, 256, 0, stream>>>(w_v, wv16, HDIM * EDIM);
  k_cvt<<<(HDIM * EDIM) / 2048, 256, 0, stream>>>(w_k, wk16, HDIM * EDIM);
  k_gemm<<<dim3(20, 64), 512, 0, stream>>>(e16, wv16, wk16, hidden, g_h, g_k,
                                           vt16, S);
  k_scal<<<MROWS / 256, 256, 0, stream>>>(S, AB);
  k_fuse<<<MROWS / 8, 320, 0, stream>>>(hidden, vt16, AB, g_v, conv_w, conv_b,
                                        out);
}

// Round 4
// 365.588 us; speedup vs baseline: 1.5047x; 1.3266x over previous
//
#include <hip/hip_runtime.h>
#include <cstddef>
#include <cstdint>

typedef __bf16 bf16;
typedef __bf16 bf16x4 __attribute__((ext_vector_type(4)));
typedef __bf16 bf16x8 __attribute__((ext_vector_type(8)));
typedef float f32x4 __attribute__((ext_vector_type(4)));

#define AS1C(p) ((const __attribute__((address_space(1))) void*)(p))
#define AS3(p)  ((__attribute__((address_space(3))) void*)(p))

#define MROWS 16384
#define HDIM 2560
#define EDIM 1024
#define LSEQ 4096

static __device__ const int kHeadOff[8] = {0, 250007, 500020, 750047,
                                           1000078, 1250115, 1500158, 1750207};

// ---------------- K1: gather emb rows -> bf16 E [MROWS][1024] ----------------
__global__ __launch_bounds__(256) void k_gather(const int* __restrict__ hidx,
                                                const float* __restrict__ emb,
                                                bf16* __restrict__ E) {
  const int m = blockIdx.x;
  const int t = threadIdx.x;
  const int head = t >> 5;          // 8 heads x 32 threads
  const int e4 = (t & 31) * 4;      // 4 floats per thread
  const int rid = hidx[m * 8 + head] + kHeadOff[head];
  const float4 v = *(const float4*)(emb + (size_t)rid * 128 + e4);
  bf16x4 o;
  o[0] = (bf16)v.x; o[1] = (bf16)v.y; o[2] = (bf16)v.z; o[3] = (bf16)v.w;
  *(bf16x4*)(E + (size_t)m * EDIM + head * 128 + e4) = o;
}

// ---------------- fp32 -> bf16 bulk convert (weights) ----------------
__global__ __launch_bounds__(256) void k_cvt(const float* __restrict__ src,
                                             bf16* __restrict__ dst, int n) {
  int i = (blockIdx.x * 256 + threadIdx.x) * 8;
  if (i + 8 > n) return;
  float4 a = *(const float4*)(src + i);
  float4 b = *(const float4*)(src + i + 4);
  bf16x8 o;
  o[0] = (bf16)a.x; o[1] = (bf16)a.y; o[2] = (bf16)a.z; o[3] = (bf16)a.w;
  o[4] = (bf16)b.x; o[5] = (bf16)b.y; o[6] = (bf16)b.z; o[7] = (bf16)b.w;
  *(bf16x8*)(dst + i) = o;
}

// reduce across the 16 lanes of each khalf group (lane = khalf*16 + r16)
__device__ __forceinline__ float red16(float v) {
  v += __shfl_xor(v, 1);
  v += __shfl_xor(v, 2);
  v += __shfl_xor(v, 4);
  v += __shfl_xor(v, 8);
  return v;
}

// ================= K2: 256x256 8-phase GEMM (T2+T3+T4+T5) ===================
// C[m][n] = sum_k A[m][k] * W[n][k];  A=[16384][1024], W=[2560][1024]
// 512 thr = 8 waves (2M x 4N); per-wave out 128x64; BK=64 (2x k=32 MFMA).
// LDS: 2 buffers x (A 32KB + B 32KB), row-major [256 rows][64 cols] bf16,
// XOR-swizzle byte ^= (row&7)<<4 (involution, both staging-source and read).
// B rows permuted so each stage unit (8KB) is LDS-contiguous.
// Block swizzle: w -> (xcd = w&7, band, gx, y) so each XCD runs a 4-row-panel
// band with y fastest -> A L2-hot, B read 4x back-to-back (T1, bijective).
// vt blocks: store Vt bf16 + S4; kt blocks: no store, S1,S2,S3. Partials
// reduced in LDS across wn-waves -> 1 global atomic per (row,comp)/block.

__device__ __forceinline__ void stA(const bf16* __restrict__ A, char* ldsc,
                                    int bufo, int q, int m0, int k0, int tid,
                                    int arow, int acolb) {
  const bf16* src = A + (size_t)(m0 + q * 64 + arow) * EDIM + k0 + (acolb >> 1);
  __builtin_amdgcn_global_load_lds(AS1C(src),
      AS3(ldsc + bufo + q * 8192 + (tid >> 6) * 1024), 16, 0, 0);
}

__device__ __forceinline__ void stB(const bf16* __restrict__ W, char* ldsc,
                                    int bufo, int u, int n0, int k0, int tid,
                                    int arow, int acolb) {
  const int L = u * 64 + arow;                       // LDS row (permuted space)
  const int wrow = ((L >> 5) & 3) * 64 + (L >> 7) * 32 + (L & 31);
  const bf16* src = W + (size_t)(n0 + wrow) * EDIM + k0 + (acolb >> 1);
  __builtin_amdgcn_global_load_lds(AS1C(src),
      AS3(ldsc + bufo + 32768 + u * 8192 + (tid >> 6) * 1024), 16, 0, 0);
}

#define RDA(BUFO, MIB) do { \
  _Pragma("unroll") for (int mi = 0; mi < 4; ++mi) { \
    a[mi][0] = *(const bf16x8*)(ldsc + (BUFO) + aBase + ((MIB) + mi) * 2048 + c0); \
    a[mi][1] = *(const bf16x8*)(ldsc + (BUFO) + aBase + ((MIB) + mi) * 2048 + (c0 ^ 64)); \
  } } while (0)

#define RDB(BUFO, DST, NJB) do { \
  _Pragma("unroll") for (int nj = 0; nj < 2; ++nj) { \
    DST[nj][0] = *(const bf16x8*)(ldsc + (BUFO) + bRowOff[(NJB) + nj] + c0); \
    DST[nj][1] = *(const bf16x8*)(ldsc + (BUFO) + bRowOff[(NJB) + nj] + (c0 ^ 64)); \
  } } while (0)

#define MFMAQ(MIOFF, NJOFF, BARR) do { \
  _Pragma("unroll") for (int mi = 0; mi < 4; ++mi) { \
    _Pragma("unroll") for (int nj = 0; nj < 2; ++nj) { \
      acc[(MIOFF) + mi][(NJOFF) + nj] = __builtin_amdgcn_mfma_f32_16x16x32_bf16( \
          a[mi][0], BARR[nj][0], acc[(MIOFF) + mi][(NJOFF) + nj], 0, 0, 0); \
      acc[(MIOFF) + mi][(NJOFF) + nj] = __builtin_amdgcn_mfma_f32_16x16x32_bf16( \
          a[mi][1], BARR[nj][1], acc[(MIOFF) + mi][(NJOFF) + nj], 0, 0, 0); \
    } } } while (0)

#define MID_SYNC() do { __builtin_amdgcn_s_barrier(); \
  asm volatile("s_waitcnt lgkmcnt(0)" ::: "memory"); \
  __builtin_amdgcn_sched_barrier(0); \
  __builtin_amdgcn_s_setprio(1); } while (0)

#define END_PHASE() do { __builtin_amdgcn_s_setprio(0); \
  __builtin_amdgcn_s_barrier(); } while (0)

#define VMCNT6() asm volatile("s_waitcnt vmcnt(6)" ::: "memory")
#define VMCNT0() asm volatile("s_waitcnt vmcnt(0)" ::: "memory")

__global__ __launch_bounds__(512) void k_gemm(const bf16* __restrict__ A,
                                              const bf16* __restrict__ Wv,
                                              const bf16* __restrict__ Wk,
                                              const float* __restrict__ hidden,
                                              const float* __restrict__ g_h,
                                              const float* __restrict__ g_k,
                                              bf16* __restrict__ Vt,
                                              float* __restrict__ S) {
  __shared__ __attribute__((aligned(128))) char ldsc[131072];
  const int tid = threadIdx.x;
  const int wid = tid >> 6, lane = tid & 63;
  const int wm = wid >> 2, wn = wid & 3;
  const int r16 = lane & 15, khalf = lane >> 4;

  // two-level XCD-aware swizzle (bijective: 1280 = 8 xcd * 2 band * 20 gx * 4 y)
  const int w = blockIdx.x;
  const int xcd = w & 7;
  const int r_ = w >> 3;               // 0..159 within-XCD slot, executed in order
  const int band = r_ / 80;            // 0..1
  const int i_ = r_ % 80;
  const int gx = i_ >> 2;              // 0..19 (column block), slow
  const int y = xcd * 8 + band * 4 + (i_ & 3);  // row panel, fast
  const int m0 = y * 256;
  const bool isV = (gx < 10);
  const int n0 = (isV ? gx : gx - 10) * 256;
  const bf16* W = isV ? Wv : Wk;

  const int BUF0 = 0, BUF1 = 65536;
  const int flip = (r16 & 7) << 4;
  const int c0 = (khalf * 16) ^ flip;
  const int aBase = (wm * 128 + r16) * 128;
  int bRowOff[4];
#pragma unroll
  for (int nj = 0; nj < 4; ++nj)
    bRowOff[nj] = ((nj >> 1) * 128 + wn * 32 + (nj & 1) * 16 + r16) * 128 + 32768;

  // staging per-thread geometry (identical for all units)
  const int arow = tid >> 3;                       // 0..63 row within unit
  const int acolb = ((tid & 7) * 16) ^ ((arow & 7) << 4);  // swizzled colbyte

  f32x4 acc[8][4] = {};
  bf16x8 a[4][2], bl[2][2], bh[2][2];

  // ---- prologue: tile0 (buf0,k=0) full; tile1 (buf1,k=64) A-lo,B-lo,B-hi ----
  stA(A, ldsc, BUF0, 0, m0, 0, tid, arow, acolb);
  stA(A, ldsc, BUF0, 2, m0, 0, tid, arow, acolb);
  stB(W, ldsc, BUF0, 0, n0, 0, tid, arow, acolb);
  stB(W, ldsc, BUF0, 1, n0, 0, tid, arow, acolb);
  stB(W, ldsc, BUF0, 2, n0, 0, tid, arow, acolb);
  stB(W, ldsc, BUF0, 3, n0, 0, tid, arow, acolb);
  stA(A, ldsc, BUF0, 1, m0, 0, tid, arow, acolb);
  stA(A, ldsc, BUF0, 3, m0, 0, tid, arow, acolb);
  stA(A, ldsc, BUF1, 0, m0, 64, tid, arow, acolb);
  stA(A, ldsc, BUF1, 2, m0, 64, tid, arow, acolb);
  stB(W, ldsc, BUF1, 0, n0, 64, tid, arow, acolb);
  stB(W, ldsc, BUF1, 1, n0, 64, tid, arow, acolb);
  stB(W, ldsc, BUF1, 2, n0, 64, tid, arow, acolb);
  stB(W, ldsc, BUF1, 3, n0, 64, tid, arow, acolb);
  VMCNT6();                       // tile0 (oldest 8 loads) landed
  __builtin_amdgcn_s_barrier();

  for (int it = 0; it < 8; ++it) {
    const int kO = it * 128 + 64;       // odd tile of this iter (buf1)
    const int kN = it * 128 + 128;      // next even tile (buf0)
    const int kN1 = kN + 64;            // next odd tile (buf1)
    const bool pf = (it < 7);

    // ph1: even tile, quad(mi0-3, nj0-1); stage A-hi(odd tile, buf1)
    RDA(BUF0, 0);
    RDB(BUF0, bl, 0);
    stA(A, ldsc, BUF1, 1, m0, kO, tid, arow, acolb);
    stA(A, ldsc, BUF1, 3, m0, kO, tid, arow, acolb);
    MID_SYNC();
    MFMAQ(0, 0, bl);
    END_PHASE();

    // ph2: quad(mi0-3, nj2-3); stage A-lo(next even, buf0)
    RDB(BUF0, bh, 2);
    if (pf) {
      stA(A, ldsc, BUF0, 0, m0, kN, tid, arow, acolb);
      stA(A, ldsc, BUF0, 2, m0, kN, tid, arow, acolb);
    }
    MID_SYNC();
    MFMAQ(0, 2, bh);
    END_PHASE();

    // ph3: quad(mi4-7, nj0-1); stage B-lo(next even)
    RDA(BUF0, 4);
    if (pf) {
      stB(W, ldsc, BUF0, 0, n0, kN, tid, arow, acolb);
      stB(W, ldsc, BUF0, 1, n0, kN, tid, arow, acolb);
    }
    MID_SYNC();
    MFMAQ(4, 0, bl);
    END_PHASE();

    // ph4: quad(mi4-7, nj2-3); stage B-hi(next even); vmcnt
    if (pf) {
      stB(W, ldsc, BUF0, 2, n0, kN, tid, arow, acolb);
      stB(W, ldsc, BUF0, 3, n0, kN, tid, arow, acolb);
      VMCNT6();                   // odd tile of this iter fully landed
    } else {
      VMCNT0();                   // tail: exact counts drift, drain once
    }
    MID_SYNC();
    MFMAQ(4, 2, bh);
    END_PHASE();

    // ph5: odd tile, quad(mi0-3, nj0-1); stage A-hi(next even, buf0)
    RDA(BUF1, 0);
    RDB(BUF1, bl, 0);
    if (pf) {
      stA(A, ldsc, BUF0, 1, m0, kN, tid, arow, acolb);
      stA(A, ldsc, BUF0, 3, m0, kN, tid, arow, acolb);
    }
    MID_SYNC();
    MFMAQ(0, 0, bl);
    END_PHASE();

    // ph6: quad(mi0-3, nj2-3); stage A-lo(next odd, buf1)
    RDB(BUF1, bh, 2);
    if (pf) {
      stA(A, ldsc, BUF1, 0, m0, kN1, tid, arow, acolb);
      stA(A, ldsc, BUF1, 2, m0, kN1, tid, arow, acolb);
    }
    MID_SYNC();
    MFMAQ(0, 2, bh);
    END_PHASE();

    // ph7: quad(mi4-7, nj0-1); stage B-lo(next odd)
    RDA(BUF1, 4);
    if (pf) {
      stB(W, ldsc, BUF1, 0, n0, kN1, tid, arow, acolb);
      stB(W, ldsc, BUF1, 1, n0, kN1, tid, arow, acolb);
    }
    MID_SYNC();
    MFMAQ(4, 0, bl);
    END_PHASE();

    // ph8: quad(mi4-7, nj2-3); stage B-hi(next odd); vmcnt
    if (pf) {
      stB(W, ldsc, BUF1, 2, n0, kN1, tid, arow, acolb);
      stB(W, ldsc, BUF1, 3, n0, kN1, tid, arow, acolb);
    }
    VMCNT6();                     // next even tile fully landed
    MID_SYNC();
    MFMAQ(4, 2, bh);
    END_PHASE();
  }

  // ---- epilogue: row = m0+wm*128+mi*16+khalf*4+r; col = n0+wn*64+nj*16+r16
  // LDS (free now, last phase ended with barrier) stages per-wn partials.
  float* P = (float*)ldsc;
  if (isV) {
#pragma unroll
    for (int mi = 0; mi < 8; ++mi) {
#pragma unroll
      for (int nj = 0; nj < 4; ++nj) {
        const int col = n0 + wn * 64 + nj * 16 + r16;
#pragma unroll
        for (int r = 0; r < 4; ++r) {
          const int row = m0 + wm * 128 + mi * 16 + khalf * 4 + r;
          Vt[(size_t)row * HDIM + col] = (bf16)acc[mi][nj][r];
        }
      }
#pragma unroll
      for (int r = 0; r < 4; ++r) {
        float p = 0.f;
#pragma unroll
        for (int nj = 0; nj < 4; ++nj) p += acc[mi][nj][r] * acc[mi][nj][r];
        p = red16(p);
        if (r16 == 0) {
          const int rl = wm * 128 + mi * 16 + khalf * 4 + r;  // 0..255
          P[wn * 256 + rl] = p;                               // unique writer
        }
      }
    }
    __syncthreads();
    for (int j = tid; j < 256; j += 512) {
      const float s = P[j] + P[256 + j] + P[512 + j] + P[768 + j];
      atomicAdd(&S[(size_t)(m0 + j) * 4 + 3], s);
    }
  } else {
    float ghk[4];
#pragma unroll
    for (int nj = 0; nj < 4; ++nj) {
      const int col = n0 + wn * 64 + nj * 16 + r16;
      ghk[nj] = g_h[col] * g_k[col];
    }
#pragma unroll
    for (int mi = 0; mi < 8; ++mi) {
#pragma unroll
      for (int r = 0; r < 4; ++r) {
        const int row = m0 + wm * 128 + mi * 16 + khalf * 4 + r;
        float p1 = 0.f, p2 = 0.f, p3 = 0.f;
#pragma unroll
        for (int nj = 0; nj < 4; ++nj) {
          const int col = n0 + wn * 64 + nj * 16 + r16;
          const float k = acc[mi][nj][r];
          const float h = hidden[(size_t)row * HDIM + col];
          p1 += h * h;
          p2 += h * ghk[nj] * k;
          p3 += k * k;
        }
        p1 = red16(p1); p2 = red16(p2); p3 = red16(p3);
        if (r16 == 0) {
          const int rl = wm * 128 + mi * 16 + khalf * 4 + r;  // 0..255
          float* Pr = P + (wn * 256 + rl) * 3;
          Pr[0] = p1; Pr[1] = p2; Pr[2] = p3;                 // unique writer
        }
      }
    }
    __syncthreads();
    for (int j = tid; j < 768; j += 512) {
      const int rl = j / 3, c = j % 3;
      const float s = P[j] + P[768 + j] + P[1536 + j] + P[2304 + j];
      atomicAdd(&S[(size_t)(m0 + rl) * 4 + c], s);
    }
  }
}

// ---------------- K3: per-row scalars -> (alpha, alpha*inv_v) ----------------
__global__ __launch_bounds__(256) void k_scal(const float* __restrict__ S,
                                              float* __restrict__ AB) {
  const int m = blockIdx.x * 256 + threadIdx.x;
  const float s1 = S[(size_t)m * 4 + 0];
  const float s2 = S[(size_t)m * 4 + 1];
  const float s3 = S[(size_t)m * 4 + 2];
  const float s4 = S[(size_t)m * 4 + 3];
  const float inv_h = rsqrtf(s1 * (1.f / HDIM) + 1e-6f);
  const float inv_k = rsqrtf(s3 * (1.f / HDIM) + 1e-6f);
  const float dot = s2 * inv_h * inv_k * 0.019764235f;  // 1/sqrt(2560)
  float st = sqrtf(fmaxf(fabsf(dot), 1e-6f));
  st = (dot < 0.f) ? -st : st;
  if (dot == 0.f) st = 0.f;
  const float alpha = 1.f / (1.f + __expf(-st));
  const float inv_v = rsqrtf(alpha * alpha * s4 * (1.f / HDIM) + 1e-6f);
  AB[(size_t)m * 2 + 0] = alpha;
  AB[(size_t)m * 2 + 1] = alpha * inv_v;
}

// ---------------- K4: fused v_tilde/v_n recompute + conv + SiLU + residuals --
__global__ __launch_bounds__(320) void k_fuse(const float* __restrict__ hidden,
                                              const bf16* __restrict__ Vt,
                                              const float* __restrict__ AB,
                                              const float* __restrict__ g_v,
                                              const float* __restrict__ conv_w,
                                              const float* __restrict__ conv_b,
                                              float* __restrict__ out) {
  const int mbase = blockIdx.x * 8;
  const int l0 = mbase & (LSEQ - 1);
  const int t = threadIdx.x;
  const int h0 = t * 8;

  float gv[8], cb[8];
  *(float4*)&gv[0] = *(const float4*)(g_v + h0);
  *(float4*)&gv[4] = *(const float4*)(g_v + h0 + 4);
  *(float4*)&cb[0] = *(const float4*)(conv_b + h0);
  *(float4*)&cb[4] = *(const float4*)(conv_b + h0 + 4);
  float4 cw[8];
#pragma unroll
  for (int i = 0; i < 8; ++i)
    cw[i] = *(const float4*)(conv_w + (size_t)(h0 + i) * 4);

  float win[4][8];
#pragma unroll
  for (int jj = 0; jj < 4; ++jj)
#pragma unroll
    for (int i = 0; i < 8; ++i) win[jj][i] = 0.f;

#pragma unroll
  for (int j = 0; j < 11; ++j) {  // source rows mbase-3 .. mbase+7
    const int lj = l0 - 3 + j;
    const int m = mbase - 3 + j;
    float vtl[8];
    if (lj >= 0) {
      const float alpha = AB[(size_t)m * 2 + 0];
      const float av = AB[(size_t)m * 2 + 1];
      const bf16x8 v = *(const bf16x8*)(Vt + (size_t)m * HDIM + h0);
#pragma unroll
      for (int i = 0; i < 8; ++i) {
        const float vt = (float)v[i];
        vtl[i] = alpha * vt;
        win[j & 3][i] = av * vt * gv[i];  // v_n
      }
    } else {
#pragma unroll
      for (int i = 0; i < 8; ++i) { win[j & 3][i] = 0.f; vtl[i] = 0.f; }
    }
    if (j >= 3) {
      const int R = mbase + j - 3;
      const size_t base = (size_t)R * HDIM + h0;
      float hx[8];
      *(float4*)&hx[0] = *(const float4*)(hidden + base);
      *(float4*)&hx[4] = *(const float4*)(hidden + base + 4);
      float o[8];
#pragma unroll
      for (int i = 0; i < 8; ++i) {
        float c = cb[i];
        c += ((const float*)&cw[i])[0] * win[(j - 3) & 3][i];
        c += ((const float*)&cw[i])[1] * win[(j - 2) & 3][i];
        c += ((const float*)&cw[i])[2] * win[(j - 1) & 3][i];
        c += ((const float*)&cw[i])[3] * win[j & 3][i];
        const float y = c / (1.f + __expf(-c));  // silu
        o[i] = hx[i] + y + vtl[i];
      }
      *(float4*)(out + base) = *(float4*)&o[0];
      *(float4*)(out + base + 4) = *(float4*)&o[4];
    }
  }
}

// ---------------- launcher ----------------
extern "C" void kernel_launch(void* const* d_in, const int* in_sizes, int n_in,
                              void* d_out, int out_size, void* d_ws,
                              size_t ws_size, hipStream_t stream) {
  const float* hidden = (const float*)d_in[0];
  const int* hashidx = (const int*)d_in[1];
  const float* emb = (const float*)d_in[2];
  const float* w_v = (const float*)d_in[3];
  const float* w_k = (const float*)d_in[4];
  const float* g_h = (const float*)d_in[5];
  const float* g_k = (const float*)d_in[6];
  const float* g_v = (const float*)d_in[7];
  const float* conv_w = (const float*)d_in[8];
  const float* conv_b = (const float*)d_in[9];
  float* out = (float*)d_out;

  char* w = (char*)d_ws;
  bf16* e16 = (bf16*)w;  w += (size_t)MROWS * EDIM * 2;   // 33.5 MB
  bf16* wv16 = (bf16*)w; w += (size_t)HDIM * EDIM * 2;    // 5.2 MB
  bf16* wk16 = (bf16*)w; w += (size_t)HDIM * EDIM * 2;    // 5.2 MB
  bf16* vt16 = (bf16*)w; w += (size_t)MROWS * HDIM * 2;   // 83.9 MB
  float* S = (float*)w;  w += (size_t)MROWS * 4 * 4;      // 256 KB
  float* AB = (float*)w; w += (size_t)MROWS * 2 * 4;      // 128 KB

  hipMemsetAsync(S, 0, (size_t)MROWS * 4 * 4, stream);
  k_gather<<<MROWS, 256, 0, stream>>>(hashidx, emb, e16);
  k_cvt<<<(HDIM * EDIM) / 2048, 256, 0, stream>>>(w_v, wv16, HDIM * EDIM);
  k_cvt<<<(HDIM * EDIM) / 2048, 256, 0, stream>>>(w_k, wk16, HDIM * EDIM);
  k_gemm<<<dim3(1280), 512, 0, stream>>>(e16, wv16, wk16, hidden, g_h, g_k,
                                         vt16, S);
  k_scal<<<MROWS / 256, 256, 0, stream>>>(S, AB);
  k_fuse<<<MROWS / 8, 320, 0, stream>>>(hidden, vt16, AB, g_v, conv_w, conv_b,
                                        out);
}

// Round 5
// 328.842 us; speedup vs baseline: 1.6728x; 1.1117x over previous
//
#include <hip/hip_runtime.h>
#include <cstddef>
#include <cstdint>

typedef __bf16 bf16;
typedef __bf16 bf16x4 __attribute__((ext_vector_type(4)));
typedef __bf16 bf16x8 __attribute__((ext_vector_type(8)));
typedef float f32x4 __attribute__((ext_vector_type(4)));

#define AS1C(p) ((const __attribute__((address_space(1))) void*)(p))
#define AS3(p)  ((__attribute__((address_space(3))) void*)(p))

#define MROWS 16384
#define HDIM 2560
#define EDIM 1024
#define LSEQ 4096

static __device__ const int kHeadOff[8] = {0, 250007, 500020, 750047,
                                           1000078, 1250115, 1500158, 1750207};

// ---------------- K1: gather emb rows -> bf16 E [MROWS][1024] ----------------
__global__ __launch_bounds__(256) void k_gather(const int* __restrict__ hidx,
                                                const float* __restrict__ emb,
                                                bf16* __restrict__ E) {
  const int m = blockIdx.x;
  const int t = threadIdx.x;
  const int head = t >> 5;          // 8 heads x 32 threads
  const int e4 = (t & 31) * 4;      // 4 floats per thread
  const int rid = hidx[m * 8 + head] + kHeadOff[head];
  const float4 v = *(const float4*)(emb + (size_t)rid * 128 + e4);
  bf16x4 o;
  o[0] = (bf16)v.x; o[1] = (bf16)v.y; o[2] = (bf16)v.z; o[3] = (bf16)v.w;
  *(bf16x4*)(E + (size_t)m * EDIM + head * 128 + e4) = o;
}

// ---------------- fp32 -> bf16 bulk convert (weights) ----------------
__global__ __launch_bounds__(256) void k_cvt(const float* __restrict__ src,
                                             bf16* __restrict__ dst, int n) {
  int i = (blockIdx.x * 256 + threadIdx.x) * 8;
  if (i + 8 > n) return;
  float4 a = *(const float4*)(src + i);
  float4 b = *(const float4*)(src + i + 4);
  bf16x8 o;
  o[0] = (bf16)a.x; o[1] = (bf16)a.y; o[2] = (bf16)a.z; o[3] = (bf16)a.w;
  o[4] = (bf16)b.x; o[5] = (bf16)b.y; o[6] = (bf16)b.z; o[7] = (bf16)b.w;
  *(bf16x8*)(dst + i) = o;
}

// reduce across the 16 lanes of each khalf group (lane = khalf*16 + r16)
__device__ __forceinline__ float red16(float v) {
  v += __shfl_xor(v, 1);
  v += __shfl_xor(v, 2);
  v += __shfl_xor(v, 4);
  v += __shfl_xor(v, 8);
  return v;
}

// ================= K2: 256x128-tile GEMM, BK=32, 2 blocks/CU ================
// C[m][n] = sum_k A[m][k] * W[n][k];  A=[16384][1024], W=[2560][1024]
// 512 thr = 8 waves (4M x 2N); per-wave out 64x64; acc[4][4] (64 VGPR).
// LDS 48KB: 2 buf x (A [256][32] 16KB + B [128][32] 8KB) -> 2 blocks/CU,
// so a co-resident block's MFMA absorbs barrier/prologue/epilogue stalls.
// Swizzle (64B rows): byte ^= ((row>>1)&3)<<4 -> 2-way alias (free, m136);
// staging source pre-swizzled with the same involution, LDS dest linear.
// 32 phases: {vmcnt(3); barrier; 8 ds_read; lgkm0; setprio1; 16 MFMA;
// setprio0; barrier; stage tile p+2 (A:2 units, B:1 unit)}.
// vt blocks: store Vt bf16 + S4 partials; kt: no store, S1,S2,S3 partials;
// partials LDS-reduced across wn -> 1 atomic per (row,comp) per block.

#define LDSB 24576  // bytes per buffer: A 16384 + B 8192

__global__ __launch_bounds__(512, 4) void k_gemm(const bf16* __restrict__ A,
                                                 const bf16* __restrict__ Wv,
                                                 const bf16* __restrict__ Wk,
                                                 const float* __restrict__ hidden,
                                                 const float* __restrict__ g_h,
                                                 const float* __restrict__ g_k,
                                                 bf16* __restrict__ Vt,
                                                 float* __restrict__ S) {
  __shared__ __attribute__((aligned(16))) char ldsc[2 * LDSB];
  const int tid = threadIdx.x;
  const int wid = tid >> 6, lane = tid & 63;
  const int wm = wid >> 1, wn = wid & 1;       // 4M x 2N
  const int r16 = lane & 15, khalf = lane >> 4;

  // XCD-aware bijective swizzle: 2560 = 8 xcd * 40 gx * 8 y
  const int w = blockIdx.x;
  const int xcd = w & 7;
  const int r_ = w >> 3;                       // 0..319
  const int gx = r_ >> 3;                      // 0..39 column block (slow)
  const int y = xcd * 8 + (r_ & 7);            // row panel (fast)
  const int m0 = y * 256;
  const bool isV = (gx < 20);
  const int n0 = (isV ? gx : gx - 20) * 128;
  const bf16* Wp = isV ? Wv : Wk;

  // read addressing (byte offsets into ldsc)
  const int sw = ((r16 >> 1) & 3) << 4;        // row-derived swizzle
  const int c0 = (khalf * 16) ^ sw;
  const int aRd = (wm * 64 + r16) * 64 + c0;             // + mi*1024 + buf
  const int bRd = 16384 + (wn * 64 + r16) * 64 + c0;     // + nj*1024 + buf

  // staging source (pre-swizzled): unit = 8KB = 128 rows x 64B
  const int srow = tid >> 2;                   // 0..127 row within unit
  const int scol = (((tid & 3) ^ ((tid >> 3) & 3))) * 8; // element offset
  const bf16* pA0 = A + (size_t)(m0 + srow) * EDIM + scol;
  const bf16* pA1 = pA0 + (size_t)128 * EDIM;
  const bf16* pB = Wp + (size_t)(n0 + srow) * EDIM + scol;
  const int ldsW = wid * 1024;                 // wave slice within unit

  f32x4 acc[4][4] = {};

#define STAGE(BUFO, KT) do {                                                   \
    __builtin_amdgcn_global_load_lds(AS1C(pA0 + (KT) * 32),                    \
        AS3(ldsc + (BUFO) + ldsW), 16, 0, 0);                                  \
    __builtin_amdgcn_global_load_lds(AS1C(pA1 + (KT) * 32),                    \
        AS3(ldsc + (BUFO) + 8192 + ldsW), 16, 0, 0);                           \
    __builtin_amdgcn_global_load_lds(AS1C(pB + (KT) * 32),                     \
        AS3(ldsc + (BUFO) + 16384 + ldsW), 16, 0, 0);                          \
    __builtin_amdgcn_sched_barrier(0);                                         \
  } while (0)

#define PHASE_CORE(BUFO) do {                                                  \
    bf16x8 aF[4], bF[4];                                                       \
    _Pragma("unroll") for (int mi = 0; mi < 4; ++mi)                           \
      aF[mi] = *(const bf16x8*)(ldsc + (BUFO) + aRd + mi * 1024);              \
    _Pragma("unroll") for (int nj = 0; nj < 4; ++nj)                           \
      bF[nj] = *(const bf16x8*)(ldsc + (BUFO) + bRd + nj * 1024);              \
    asm volatile("s_waitcnt lgkmcnt(0)" ::: "memory");                         \
    __builtin_amdgcn_sched_barrier(0);                                         \
    __builtin_amdgcn_s_setprio(1);                                             \
    _Pragma("unroll") for (int mi = 0; mi < 4; ++mi)                           \
      _Pragma("unroll") for (int nj = 0; nj < 4; ++nj)                         \
        acc[mi][nj] = __builtin_amdgcn_mfma_f32_16x16x32_bf16(                 \
            aF[mi], bF[nj], acc[mi][nj], 0, 0, 0);                             \
    __builtin_amdgcn_s_setprio(0);                                             \
    __builtin_amdgcn_s_barrier();                                              \
  } while (0)

#define VMCNT3() asm volatile("s_waitcnt vmcnt(3)" ::: "memory")
#define VMCNT0() asm volatile("s_waitcnt vmcnt(0)" ::: "memory")

  // prologue: stage tiles 0,1 (6 units in flight)
  STAGE(0, 0);
  STAGE(LDSB, 1);

  // phases 0..29: steady state (stage p+2 after compute)
  for (int p = 0; p < 30; p += 2) {
    VMCNT3();
    __builtin_amdgcn_s_barrier();
    PHASE_CORE(0);
    STAGE(0, p + 2);
    VMCNT3();
    __builtin_amdgcn_s_barrier();
    PHASE_CORE(LDSB);
    STAGE(LDSB, p + 3);
  }
  // phase 30 (no stage)
  VMCNT3();
  __builtin_amdgcn_s_barrier();
  PHASE_CORE(0);
  // phase 31 (drain)
  VMCNT0();
  __builtin_amdgcn_s_barrier();
  PHASE_CORE(LDSB);

  // ---- epilogue: row = m0+wm*64+mi*16+khalf*4+r; col = n0+wn*64+nj*16+r16
  float* P = (float*)ldsc;  // free after final barrier (all stages drained)
  if (isV) {
#pragma unroll
    for (int mi = 0; mi < 4; ++mi) {
#pragma unroll
      for (int nj = 0; nj < 4; ++nj) {
        const int col = n0 + wn * 64 + nj * 16 + r16;
#pragma unroll
        for (int r = 0; r < 4; ++r) {
          const int row = m0 + wm * 64 + mi * 16 + khalf * 4 + r;
          Vt[(size_t)row * HDIM + col] = (bf16)acc[mi][nj][r];
        }
      }
#pragma unroll
      for (int r = 0; r < 4; ++r) {
        float p = 0.f;
#pragma unroll
        for (int nj = 0; nj < 4; ++nj) p += acc[mi][nj][r] * acc[mi][nj][r];
        p = red16(p);
        if (r16 == 0) {
          const int rl = wm * 64 + mi * 16 + khalf * 4 + r;  // 0..255
          P[wn * 256 + rl] = p;
        }
      }
    }
    __syncthreads();
    if (tid < 256) {
      const float s = P[tid] + P[256 + tid];
      atomicAdd(&S[(size_t)(m0 + tid) * 4 + 3], s);
    }
  } else {
    float ghk[4];
#pragma unroll
    for (int nj = 0; nj < 4; ++nj) {
      const int col = n0 + wn * 64 + nj * 16 + r16;
      ghk[nj] = g_h[col] * g_k[col];
    }
#pragma unroll
    for (int mi = 0; mi < 4; ++mi) {
#pragma unroll
      for (int r = 0; r < 4; ++r) {
        const int row = m0 + wm * 64 + mi * 16 + khalf * 4 + r;
        float p1 = 0.f, p2 = 0.f, p3 = 0.f;
#pragma unroll
        for (int nj = 0; nj < 4; ++nj) {
          const int col = n0 + wn * 64 + nj * 16 + r16;
          const float k = acc[mi][nj][r];
          const float h = hidden[(size_t)row * HDIM + col];
          p1 += h * h;
          p2 += h * ghk[nj] * k;
          p3 += k * k;
        }
        p1 = red16(p1); p2 = red16(p2); p3 = red16(p3);
        if (r16 == 0) {
          const int rl = wm * 64 + mi * 16 + khalf * 4 + r;  // 0..255
          float* Pr = P + (wn * 256 + rl) * 3;
          Pr[0] = p1; Pr[1] = p2; Pr[2] = p3;
        }
      }
    }
    __syncthreads();
    for (int j = tid; j < 768; j += 512) {
      const int rl = j / 3, c = j % 3;
      const float s = P[j] + P[768 + j];
      atomicAdd(&S[(size_t)(m0 + rl) * 4 + c], s);
    }
  }
#undef STAGE
#undef PHASE_CORE
#undef VMCNT3
#undef VMCNT0
}

// ---------------- K3: per-row scalars -> (alpha, alpha*inv_v) ----------------
__global__ __launch_bounds__(256) void k_scal(const float* __restrict__ S,
                                              float* __restrict__ AB) {
  const int m = blockIdx.x * 256 + threadIdx.x;
  const float s1 = S[(size_t)m * 4 + 0];
  const float s2 = S[(size_t)m * 4 + 1];
  const float s3 = S[(size_t)m * 4 + 2];
  const float s4 = S[(size_t)m * 4 + 3];
  const float inv_h = rsqrtf(s1 * (1.f / HDIM) + 1e-6f);
  const float inv_k = rsqrtf(s3 * (1.f / HDIM) + 1e-6f);
  const float dot = s2 * inv_h * inv_k * 0.019764235f;  // 1/sqrt(2560)
  float st = sqrtf(fmaxf(fabsf(dot), 1e-6f));
  st = (dot < 0.f) ? -st : st;
  if (dot == 0.f) st = 0.f;
  const float alpha = 1.f / (1.f + __expf(-st));
  const float inv_v = rsqrtf(alpha * alpha * s4 * (1.f / HDIM) + 1e-6f);
  AB[(size_t)m * 2 + 0] = alpha;
  AB[(size_t)m * 2 + 1] = alpha * inv_v;
}

// ---------------- K4: fused v_tilde/v_n recompute + conv + SiLU + residuals --
__global__ __launch_bounds__(320) void k_fuse(const float* __restrict__ hidden,
                                              const bf16* __restrict__ Vt,
                                              const float* __restrict__ AB,
                                              const float* __restrict__ g_v,
                                              const float* __restrict__ conv_w,
                                              const float* __restrict__ conv_b,
                                              float* __restrict__ out) {
  const int mbase = blockIdx.x * 8;
  const int l0 = mbase & (LSEQ - 1);
  const int t = threadIdx.x;
  const int h0 = t * 8;

  float gv[8], cb[8];
  *(float4*)&gv[0] = *(const float4*)(g_v + h0);
  *(float4*)&gv[4] = *(const float4*)(g_v + h0 + 4);
  *(float4*)&cb[0] = *(const float4*)(conv_b + h0);
  *(float4*)&cb[4] = *(const float4*)(conv_b + h0 + 4);
  float4 cw[8];
#pragma unroll
  for (int i = 0; i < 8; ++i)
    cw[i] = *(const float4*)(conv_w + (size_t)(h0 + i) * 4);

  float win[4][8];
#pragma unroll
  for (int jj = 0; jj < 4; ++jj)
#pragma unroll
    for (int i = 0; i < 8; ++i) win[jj][i] = 0.f;

#pragma unroll
  for (int j = 0; j < 11; ++j) {  // source rows mbase-3 .. mbase+7
    const int lj = l0 - 3 + j;
    const int m = mbase - 3 + j;
    float vtl[8];
    if (lj >= 0) {
      const float alpha = AB[(size_t)m * 2 + 0];
      const float av = AB[(size_t)m * 2 + 1];
      const bf16x8 v = *(const bf16x8*)(Vt + (size_t)m * HDIM + h0);
#pragma unroll
      for (int i = 0; i < 8; ++i) {
        const float vt = (float)v[i];
        vtl[i] = alpha * vt;
        win[j & 3][i] = av * vt * gv[i];  // v_n
      }
    } else {
#pragma unroll
      for (int i = 0; i < 8; ++i) { win[j & 3][i] = 0.f; vtl[i] = 0.f; }
    }
    if (j >= 3) {
      const int R = mbase + j - 3;
      const size_t base = (size_t)R * HDIM + h0;
      float hx[8];
      *(float4*)&hx[0] = *(const float4*)(hidden + base);
      *(float4*)&hx[4] = *(const float4*)(hidden + base + 4);
      float o[8];
#pragma unroll
      for (int i = 0; i < 8; ++i) {
        float c = cb[i];
        c += ((const float*)&cw[i])[0] * win[(j - 3) & 3][i];
        c += ((const float*)&cw[i])[1] * win[(j - 2) & 3][i];
        c += ((const float*)&cw[i])[2] * win[(j - 1) & 3][i];
        c += ((const float*)&cw[i])[3] * win[j & 3][i];
        const float y = c / (1.f + __expf(-c));  // silu
        o[i] = hx[i] + y + vtl[i];
      }
      *(float4*)(out + base) = *(float4*)&o[0];
      *(float4*)(out + base + 4) = *(float4*)&o[4];
    }
  }
}

// ---------------- launcher ----------------
extern "C" void kernel_launch(void* const* d_in, const int* in_sizes, int n_in,
                              void* d_out, int out_size, void* d_ws,
                              size_t ws_size, hipStream_t stream) {
  const float* hidden = (const float*)d_in[0];
  const int* hashidx = (const int*)d_in[1];
  const float* emb = (const float*)d_in[2];
  const float* w_v = (const float*)d_in[3];
  const float* w_k = (const float*)d_in[4];
  const float* g_h = (const float*)d_in[5];
  const float* g_k = (const float*)d_in[6];
  const float* g_v = (const float*)d_in[7];
  const float* conv_w = (const float*)d_in[8];
  const float* conv_b = (const float*)d_in[9];
  float* out = (float*)d_out;

  char* w = (char*)d_ws;
  bf16* e16 = (bf16*)w;  w += (size_t)MROWS * EDIM * 2;   // 33.5 MB
  bf16* wv16 = (bf16*)w; w += (size_t)HDIM * EDIM * 2;    // 5.2 MB
  bf16* wk16 = (bf16*)w; w += (size_t)HDIM * EDIM * 2;    // 5.2 MB
  bf16* vt16 = (bf16*)w; w += (size_t)MROWS * HDIM * 2;   // 83.9 MB
  float* S = (float*)w;  w += (size_t)MROWS * 4 * 4;      // 256 KB
  float* AB = (float*)w; w += (size_t)MROWS * 2 * 4;      // 128 KB

  hipMemsetAsync(S, 0, (size_t)MROWS * 4 * 4, stream);
  k_gather<<<MROWS, 256, 0, stream>>>(hashidx, emb, e16);
  k_cvt<<<(HDIM * EDIM) / 2048, 256, 0, stream>>>(w_v, wv16, HDIM * EDIM);
  k_cvt<<<(HDIM * EDIM) / 2048, 256, 0, stream>>>(w_k, wk16, HDIM * EDIM);
  k_gemm<<<dim3(2560), 512, 0, stream>>>(e16, wv16, wk16, hidden, g_h, g_k,
                                         vt16, S);
  k_scal<<<MROWS / 256, 256, 0, stream>>>(S, AB);
  k_fuse<<<MROWS / 8, 320, 0, stream>>>(hidden, vt16, AB, g_v, conv_w, conv_b,
                                        out);
}

// Round 6
// 325.415 us; speedup vs baseline: 1.6904x; 1.0105x over previous
//
#include <hip/hip_runtime.h>
#include <cstddef>
#include <cstdint>

typedef __bf16 bf16;
typedef __bf16 bf16x4 __attribute__((ext_vector_type(4)));
typedef __bf16 bf16x8 __attribute__((ext_vector_type(8)));
typedef float f32x4 __attribute__((ext_vector_type(4)));

#define AS1C(p) ((const __attribute__((address_space(1))) void*)(p))
#define AS3(p)  ((__attribute__((address_space(3))) void*)(p))

#define MROWS 16384
#define HDIM 2560
#define EDIM 1024
#define LSEQ 4096

static __device__ const int kHeadOff[8] = {0, 250007, 500020, 750047,
                                           1000078, 1250115, 1500158, 1750207};

// ---------------- K1: gather emb rows -> bf16 E [MROWS][1024] ----------------
// 2 rows/block; per lane: 32B read, 16B coalesced write.
__global__ __launch_bounds__(256) void k_gather(const int* __restrict__ hidx,
                                                const float* __restrict__ emb,
                                                bf16* __restrict__ E) {
  const int t = threadIdx.x;
  const int m = blockIdx.x * 2 + (t >> 7);
  const int tt = t & 127;
  const int head = tt >> 4;         // 8 heads x 16 lanes
  const int e8 = (tt & 15) * 8;     // 8 floats per lane
  const int rid = hidx[m * 8 + head] + kHeadOff[head];
  const float4 v0 = *(const float4*)(emb + (size_t)rid * 128 + e8);
  const float4 v1 = *(const float4*)(emb + (size_t)rid * 128 + e8 + 4);
  bf16x8 o;
  o[0] = (bf16)v0.x; o[1] = (bf16)v0.y; o[2] = (bf16)v0.z; o[3] = (bf16)v0.w;
  o[4] = (bf16)v1.x; o[5] = (bf16)v1.y; o[6] = (bf16)v1.z; o[7] = (bf16)v1.w;
  *(bf16x8*)(E + (size_t)m * EDIM + head * 128 + e8) = o;
}

// ---------------- fp32 -> bf16 bulk convert (both weights, one launch) ------
__global__ __launch_bounds__(256) void k_cvt2(const float* __restrict__ s0,
                                              bf16* __restrict__ d0,
                                              const float* __restrict__ s1,
                                              bf16* __restrict__ d1) {
  int b = blockIdx.x;
  const float* src = s0;
  bf16* dst = d0;
  if (b >= 1280) { b -= 1280; src = s1; dst = d1; }
  const int i = (b * 256 + threadIdx.x) * 8;
  float4 a = *(const float4*)(src + i);
  float4 c = *(const float4*)(src + i + 4);
  bf16x8 o;
  o[0] = (bf16)a.x; o[1] = (bf16)a.y; o[2] = (bf16)a.z; o[3] = (bf16)a.w;
  o[4] = (bf16)c.x; o[5] = (bf16)c.y; o[6] = (bf16)c.z; o[7] = (bf16)c.w;
  *(bf16x8*)(dst + i) = o;
}

// reduce across the 16 lanes of each khalf group (lane = khalf*16 + r16)
__device__ __forceinline__ float red16(float v) {
  v += __shfl_xor(v, 1);
  v += __shfl_xor(v, 2);
  v += __shfl_xor(v, 4);
  v += __shfl_xor(v, 8);
  return v;
}

// ================= K2: 256x128-tile GEMM, BK=32, 2 blocks/CU ================
// C[m][n] = sum_k A[m][k] * W[n][k];  A=[16384][1024], W=[2560][1024]
// 512 thr = 8 waves (4M x 2N); per-wave out 64x64; acc[4][4] (64 VGPR).
// LDS 48KB: 2 buf x (A [256][32] 16KB + B [128][32] 8KB) -> 2 blocks/CU.
// Phase: {vmcnt(3); barrier; 8 ds_read; MFMA x16 (COMPILER fine-grained
// lgkm waits - no forced drain); lgkm(0); barrier; stage tile p+2}.
// Swizzle (64B rows): byte ^= ((row>>1)&3)<<4 (2-way alias free, m136);
// source pre-swizzled with same involution, LDS dest linear.
// vt blocks: store Vt bf16 + S4 partials; kt: no store, S1,S2,S3 partials;
// partials LDS-reduced across wn -> 1 atomic per (row,comp) per block.

#define LDSB 24576  // bytes per buffer: A 16384 + B 8192

__global__ __launch_bounds__(512, 4) void k_gemm(const bf16* __restrict__ A,
                                                 const bf16* __restrict__ Wv,
                                                 const bf16* __restrict__ Wk,
                                                 const float* __restrict__ hidden,
                                                 const float* __restrict__ g_h,
                                                 const float* __restrict__ g_k,
                                                 bf16* __restrict__ Vt,
                                                 float* __restrict__ S) {
  __shared__ __attribute__((aligned(16))) char ldsc[2 * LDSB];
  const int tid = threadIdx.x;
  const int wid = tid >> 6, lane = tid & 63;
  const int wm = wid >> 1, wn = wid & 1;       // 4M x 2N
  const int r16 = lane & 15, khalf = lane >> 4;

  // XCD-aware bijective swizzle: 2560 = 8 xcd * 40 gx * 8 y
  const int w = blockIdx.x;
  const int xcd = w & 7;
  const int r_ = w >> 3;                       // 0..319
  const int gx = r_ >> 3;                      // 0..39 column block (slow)
  const int y = xcd * 8 + (r_ & 7);            // row panel (fast)
  const int m0 = y * 256;
  const bool isV = (gx < 20);
  const int n0 = (isV ? gx : gx - 20) * 128;
  const bf16* Wp = isV ? Wv : Wk;

  // read addressing (byte offsets into ldsc)
  const int sw = ((r16 >> 1) & 3) << 4;        // row-derived swizzle
  const int c0 = (khalf * 16) ^ sw;
  const int aRd = (wm * 64 + r16) * 64 + c0;             // + mi*1024 + buf
  const int bRd = 16384 + (wn * 64 + r16) * 64 + c0;     // + nj*1024 + buf

  // staging source (pre-swizzled): unit = 8KB = 128 rows x 64B
  const int srow = tid >> 2;                   // 0..127 row within unit
  const int scol = (((tid & 3) ^ ((tid >> 3) & 3))) * 8; // element offset
  const bf16* pA0 = A + (size_t)(m0 + srow) * EDIM + scol;
  const bf16* pA1 = pA0 + (size_t)128 * EDIM;
  const bf16* pB = Wp + (size_t)(n0 + srow) * EDIM + scol;
  const int ldsW = wid * 1024;                 // wave slice within unit

  f32x4 acc[4][4] = {};

#define STAGE(BUFO, KT) do {                                                   \
    __builtin_amdgcn_global_load_lds(AS1C(pA0 + (KT) * 32),                    \
        AS3(ldsc + (BUFO) + ldsW), 16, 0, 0);                                  \
    __builtin_amdgcn_global_load_lds(AS1C(pA1 + (KT) * 32),                    \
        AS3(ldsc + (BUFO) + 8192 + ldsW), 16, 0, 0);                           \
    __builtin_amdgcn_global_load_lds(AS1C(pB + (KT) * 32),                     \
        AS3(ldsc + (BUFO) + 16384 + ldsW), 16, 0, 0);                          \
    __builtin_amdgcn_sched_barrier(0);                                         \
  } while (0)

  // No forced pre-MFMA drain: compiler emits fine-grained lgkmcnt(3/2/1/0)
  // as each bF lands (m97 asm evidence). lgkm(0) AFTER the MFMAs guarantees
  // all reads of this buffer completed before the end barrier -> safe restage.
#define PHASE_CORE(BUFO) do {                                                  \
    bf16x8 aF[4], bF[4];                                                       \
    _Pragma("unroll") for (int mi = 0; mi < 4; ++mi)                           \
      aF[mi] = *(const bf16x8*)(ldsc + (BUFO) + aRd + mi * 1024);              \
    _Pragma("unroll") for (int nj = 0; nj < 4; ++nj)                           \
      bF[nj] = *(const bf16x8*)(ldsc + (BUFO) + bRd + nj * 1024);              \
    __builtin_amdgcn_s_setprio(1);                                             \
    _Pragma("unroll") for (int nj = 0; nj < 4; ++nj)                           \
      _Pragma("unroll") for (int mi = 0; mi < 4; ++mi)                         \
        acc[mi][nj] = __builtin_amdgcn_mfma_f32_16x16x32_bf16(                 \
            aF[mi], bF[nj], acc[mi][nj], 0, 0, 0);                             \
    __builtin_amdgcn_s_setprio(0);                                             \
    asm volatile("s_waitcnt lgkmcnt(0)" ::: "memory");                         \
    __builtin_amdgcn_s_barrier();                                              \
  } while (0)

#define BEGIN_PHASE3() do {                                                    \
    asm volatile("s_waitcnt vmcnt(3)" ::: "memory");                           \
    __builtin_amdgcn_s_barrier();                                              \
    asm volatile("" ::: "memory");                                             \
  } while (0)

#define BEGIN_PHASE0() do {                                                    \
    asm volatile("s_waitcnt vmcnt(0)" ::: "memory");                           \
    __builtin_amdgcn_s_barrier();                                              \
    asm volatile("" ::: "memory");                                             \
  } while (0)

  // prologue: stage tiles 0,1 (6 units in flight)
  STAGE(0, 0);
  STAGE(LDSB, 1);

  // steady state: tiles p (buf0), p+1 (buf1); stage p+2, p+3
  for (int p = 0; p < 30; p += 2) {
    BEGIN_PHASE3();
    PHASE_CORE(0);
    STAGE(0, p + 2);
    BEGIN_PHASE3();
    PHASE_CORE(LDSB);
    STAGE(LDSB, p + 3);
  }
  // tile 30 (no stage)
  BEGIN_PHASE3();
  PHASE_CORE(0);
  // tile 31 (drain)
  BEGIN_PHASE0();
  PHASE_CORE(LDSB);

  // ---- epilogue: row = m0+wm*64+mi*16+khalf*4+r; col = n0+wn*64+nj*16+r16
  float* P = (float*)ldsc;  // free after final barrier (all stages drained)
  if (isV) {
#pragma unroll
    for (int mi = 0; mi < 4; ++mi) {
#pragma unroll
      for (int nj = 0; nj < 4; ++nj) {
        const int col = n0 + wn * 64 + nj * 16 + r16;
#pragma unroll
        for (int r = 0; r < 4; ++r) {
          const int row = m0 + wm * 64 + mi * 16 + khalf * 4 + r;
          Vt[(size_t)row * HDIM + col] = (bf16)acc[mi][nj][r];
        }
      }
#pragma unroll
      for (int r = 0; r < 4; ++r) {
        float p = 0.f;
#pragma unroll
        for (int nj = 0; nj < 4; ++nj) p += acc[mi][nj][r] * acc[mi][nj][r];
        p = red16(p);
        if (r16 == 0) {
          const int rl = wm * 64 + mi * 16 + khalf * 4 + r;  // 0..255
          P[wn * 256 + rl] = p;
        }
      }
    }
    __syncthreads();
    if (tid < 256) {
      const float s = P[tid] + P[256 + tid];
      atomicAdd(&S[(size_t)(m0 + tid) * 4 + 3], s);
    }
  } else {
    float ghk[4];
#pragma unroll
    for (int nj = 0; nj < 4; ++nj) {
      const int col = n0 + wn * 64 + nj * 16 + r16;
      ghk[nj] = g_h[col] * g_k[col];
    }
#pragma unroll
    for (int mi = 0; mi < 4; ++mi) {
#pragma unroll
      for (int r = 0; r < 4; ++r) {
        const int row = m0 + wm * 64 + mi * 16 + khalf * 4 + r;
        float p1 = 0.f, p2 = 0.f, p3 = 0.f;
#pragma unroll
        for (int nj = 0; nj < 4; ++nj) {
          const int col = n0 + wn * 64 + nj * 16 + r16;
          const float k = acc[mi][nj][r];
          const float h = hidden[(size_t)row * HDIM + col];
          p1 += h * h;
          p2 += h * ghk[nj] * k;
          p3 += k * k;
        }
        p1 = red16(p1); p2 = red16(p2); p3 = red16(p3);
        if (r16 == 0) {
          const int rl = wm * 64 + mi * 16 + khalf * 4 + r;  // 0..255
          float* Pr = P + (wn * 256 + rl) * 3;
          Pr[0] = p1; Pr[1] = p2; Pr[2] = p3;
        }
      }
    }
    __syncthreads();
    for (int j = tid; j < 768; j += 512) {
      const int rl = j / 3, c = j % 3;
      const float s = P[j] + P[768 + j];
      atomicAdd(&S[(size_t)(m0 + rl) * 4 + c], s);
    }
  }
#undef STAGE
#undef PHASE_CORE
#undef BEGIN_PHASE3
#undef BEGIN_PHASE0
}

// ---------------- K3: per-row scalars -> (alpha, alpha*inv_v) ----------------
__global__ __launch_bounds__(256) void k_scal(const float* __restrict__ S,
                                              float* __restrict__ AB) {
  const int m = blockIdx.x * 256 + threadIdx.x;
  const float s1 = S[(size_t)m * 4 + 0];
  const float s2 = S[(size_t)m * 4 + 1];
  const float s3 = S[(size_t)m * 4 + 2];
  const float s4 = S[(size_t)m * 4 + 3];
  const float inv_h = rsqrtf(s1 * (1.f / HDIM) + 1e-6f);
  const float inv_k = rsqrtf(s3 * (1.f / HDIM) + 1e-6f);
  const float dot = s2 * inv_h * inv_k * 0.019764235f;  // 1/sqrt(2560)
  float st = sqrtf(fmaxf(fabsf(dot), 1e-6f));
  st = (dot < 0.f) ? -st : st;
  if (dot == 0.f) st = 0.f;
  const float alpha = 1.f / (1.f + __expf(-st));
  const float inv_v = rsqrtf(alpha * alpha * s4 * (1.f / HDIM) + 1e-6f);
  AB[(size_t)m * 2 + 0] = alpha;
  AB[(size_t)m * 2 + 1] = alpha * inv_v;
}

// ---------------- K4: fused v_tilde/v_n recompute + conv + SiLU + residuals --
__global__ __launch_bounds__(320) void k_fuse(const float* __restrict__ hidden,
                                              const bf16* __restrict__ Vt,
                                              const float* __restrict__ AB,
                                              const float* __restrict__ g_v,
                                              const float* __restrict__ conv_w,
                                              const float* __restrict__ conv_b,
                                              float* __restrict__ out) {
  const int mbase = blockIdx.x * 8;
  const int l0 = mbase & (LSEQ - 1);
  const int t = threadIdx.x;
  const int h0 = t * 8;

  float gv[8], cb[8];
  *(float4*)&gv[0] = *(const float4*)(g_v + h0);
  *(float4*)&gv[4] = *(const float4*)(g_v + h0 + 4);
  *(float4*)&cb[0] = *(const float4*)(conv_b + h0);
  *(float4*)&cb[4] = *(const float4*)(conv_b + h0 + 4);
  float4 cw[8];
#pragma unroll
  for (int i = 0; i < 8; ++i)
    cw[i] = *(const float4*)(conv_w + (size_t)(h0 + i) * 4);

  float win[4][8];
#pragma unroll
  for (int jj = 0; jj < 4; ++jj)
#pragma unroll
    for (int i = 0; i < 8; ++i) win[jj][i] = 0.f;

#pragma unroll
  for (int j = 0; j < 11; ++j) {  // source rows mbase-3 .. mbase+7
    const int lj = l0 - 3 + j;
    const int m = mbase - 3 + j;
    float vtl[8];
    if (lj >= 0) {
      const float alpha = AB[(size_t)m * 2 + 0];
      const float av = AB[(size_t)m * 2 + 1];
      const bf16x8 v = *(const bf16x8*)(Vt + (size_t)m * HDIM + h0);
#pragma unroll
      for (int i = 0; i < 8; ++i) {
        const float vt = (float)v[i];
        vtl[i] = alpha * vt;
        win[j & 3][i] = av * vt * gv[i];  // v_n
      }
    } else {
#pragma unroll
      for (int i = 0; i < 8; ++i) { win[j & 3][i] = 0.f; vtl[i] = 0.f; }
    }
    if (j >= 3) {
      const int R = mbase + j - 3;
      const size_t base = (size_t)R * HDIM + h0;
      float hx[8];
      *(float4*)&hx[0] = *(const float4*)(hidden + base);
      *(float4*)&hx[4] = *(const float4*)(hidden + base + 4);
      float o[8];
#pragma unroll
      for (int i = 0; i < 8; ++i) {
        float c = cb[i];
        c += ((const float*)&cw[i])[0] * win[(j - 3) & 3][i];
        c += ((const float*)&cw[i])[1] * win[(j - 2) & 3][i];
        c += ((const float*)&cw[i])[2] * win[(j - 1) & 3][i];
        c += ((const float*)&cw[i])[3] * win[j & 3][i];
        const float y = c / (1.f + __expf(-c));  // silu
        o[i] = hx[i] + y + vtl[i];
      }
      *(float4*)(out + base) = *(float4*)&o[0];
      *(float4*)(out + base + 4) = *(float4*)&o[4];
    }
  }
}

// ---------------- launcher ----------------
extern "C" void kernel_launch(void* const* d_in, const int* in_sizes, int n_in,
                              void* d_out, int out_size, void* d_ws,
                              size_t ws_size, hipStream_t stream) {
  const float* hidden = (const float*)d_in[0];
  const int* hashidx = (const int*)d_in[1];
  const float* emb = (const float*)d_in[2];
  const float* w_v = (const float*)d_in[3];
  const float* w_k = (const float*)d_in[4];
  const float* g_h = (const float*)d_in[5];
  const float* g_k = (const float*)d_in[6];
  const float* g_v = (const float*)d_in[7];
  const float* conv_w = (const float*)d_in[8];
  const float* conv_b = (const float*)d_in[9];
  float* out = (float*)d_out;

  char* w = (char*)d_ws;
  bf16* e16 = (bf16*)w;  w += (size_t)MROWS * EDIM * 2;   // 33.5 MB
  bf16* wv16 = (bf16*)w; w += (size_t)HDIM * EDIM * 2;    // 5.2 MB
  bf16* wk16 = (bf16*)w; w += (size_t)HDIM * EDIM * 2;    // 5.2 MB
  bf16* vt16 = (bf16*)w; w += (size_t)MROWS * HDIM * 2;   // 83.9 MB
  float* S = (float*)w;  w += (size_t)MROWS * 4 * 4;      // 256 KB
  float* AB = (float*)w; w += (size_t)MROWS * 2 * 4;      // 128 KB

  hipMemsetAsync(S, 0, (size_t)MROWS * 4 * 4, stream);
  k_gather<<<MROWS / 2, 256, 0, stream>>>(hashidx, emb, e16);
  k_cvt2<<<2560, 256, 0, stream>>>(w_v, wv16, w_k, wk16);
  k_gemm<<<dim3(2560), 512, 0, stream>>>(e16, wv16, wk16, hidden, g_h, g_k,
                                         vt16, S);
  k_scal<<<MROWS / 256, 256, 0, stream>>>(S, AB);
  k_fuse<<<MROWS / 8, 320, 0, stream>>>(hidden, vt16, AB, g_v, conv_w, conv_b,
                                        out);
}